// Round 1
// baseline (327.237 us; speedup 1.0000x reference)
//
#include <hip/hip_runtime.h>
#include <cstdint>
#include <cstddef>

#define D_MODEL 1024
#define D_STATE 64
#define SEQ     4096
#define BATCH   2
#define MROWS   (BATCH*SEQ)   // 8192 rows of activations
#define KDIM    (2*D_MODEL)   // 2048: hi|lo split K

typedef __bf16 bf16x8 __attribute__((ext_vector_type(8)));
typedef float  f32x4  __attribute__((ext_vector_type(4)));
typedef unsigned short u16;
typedef unsigned int   u32;

__device__ __forceinline__ u16 f2bf(float x) {
    u32 u = __float_as_uint(x);
    u32 r = u + 0x7FFFu + ((u >> 16) & 1u);   // round-to-nearest-even on bf16 boundary
    return (u16)(r >> 16);
}
__device__ __forceinline__ float bf2f(u16 h) {
    return __uint_as_float(((u32)h) << 16);
}

// ---------------------------------------------------------------------------
// prep: x -> A (hi|lo bf16, [8192][2048]); Win -> Bw1 ([1024][2048] = [W|W]);
//       Wout -> Bw2. One block per source row (1024 floats), 256 thr x float4.
// ---------------------------------------------------------------------------
__global__ __launch_bounds__(256) void prep_kernel(
    const float* __restrict__ x, const float* __restrict__ Win,
    const float* __restrict__ Wout,
    u16* __restrict__ Ax, u16* __restrict__ Bw1, u16* __restrict__ Bw2)
{
    const int blk = blockIdx.x, tid = threadIdx.x;
    const int k = tid * 4;
    if (blk < MROWS) {
        const float4 v = *reinterpret_cast<const float4*>(x + (size_t)blk * D_MODEL + k);
        u16 h0 = f2bf(v.x), h1 = f2bf(v.y), h2 = f2bf(v.z), h3 = f2bf(v.w);
        u16 l0 = f2bf(v.x - bf2f(h0)), l1 = f2bf(v.y - bf2f(h1));
        u16 l2 = f2bf(v.z - bf2f(h2)), l3 = f2bf(v.w - bf2f(h3));
        *reinterpret_cast<uint2*>(Ax + (size_t)blk * KDIM + k) =
            make_uint2((u32)h0 | ((u32)h1 << 16), (u32)h2 | ((u32)h3 << 16));
        *reinterpret_cast<uint2*>(Ax + (size_t)blk * KDIM + D_MODEL + k) =
            make_uint2((u32)l0 | ((u32)l1 << 16), (u32)l2 | ((u32)l3 << 16));
    } else if (blk < MROWS + D_MODEL) {
        const int row = blk - MROWS;
        const float4 v = *reinterpret_cast<const float4*>(Win + (size_t)row * D_MODEL + k);
        u32 w0 = (u32)f2bf(v.x) | ((u32)f2bf(v.y) << 16);
        u32 w1 = (u32)f2bf(v.z) | ((u32)f2bf(v.w) << 16);
        *reinterpret_cast<uint2*>(Bw1 + (size_t)row * KDIM + k) = make_uint2(w0, w1);
        *reinterpret_cast<uint2*>(Bw1 + (size_t)row * KDIM + D_MODEL + k) = make_uint2(w0, w1);
    } else {
        const int row = blk - MROWS - D_MODEL;
        const float4 v = *reinterpret_cast<const float4*>(Wout + (size_t)row * D_MODEL + k);
        u32 w0 = (u32)f2bf(v.x) | ((u32)f2bf(v.y) << 16);
        u32 w1 = (u32)f2bf(v.z) | ((u32)f2bf(v.w) << 16);
        *reinterpret_cast<uint2*>(Bw2 + (size_t)row * KDIM + k) = make_uint2(w0, w1);
        *reinterpret_cast<uint2*>(Bw2 + (size_t)row * KDIM + D_MODEL + k) = make_uint2(w0, w1);
    }
}

// ---------------------------------------------------------------------------
// gemm_bt: out[m, c] = sum_k A[m,k]*Bm[c,k] + bias[c]
// 128x128 tile, 256 thr = 4 waves (2x2 of 64x64), BK=64, mfma 16x16x32 bf16.
// MODE 0: normal [m][1024] fp32 store (out_proj -> d_out)
// MODE 1: transposed store into u_t[b][c][l] (in_proj -> scan input)
// ---------------------------------------------------------------------------
template<int MODE>
__global__ __launch_bounds__(256) void gemm_bt(
    const u16* __restrict__ A, const u16* __restrict__ Bm,
    const float* __restrict__ bias, float* __restrict__ out)
{
    __shared__ u16 As[128 * 72];   // pad row to 72 (144B = 9x16B)
    __shared__ u16 Bs[128 * 72];
    const int m0 = blockIdx.y * 128, n0 = blockIdx.x * 128;
    const int tid = threadIdx.x;
    const int wave = tid >> 6, lane = tid & 63;
    const int wm = wave >> 1, wn = wave & 1;
    const int qm = lane & 15, qk = lane >> 4;
    f32x4 acc[4][4] = {};
    for (int k0 = 0; k0 < KDIM; k0 += 64) {
        #pragma unroll
        for (int it = 0; it < 4; ++it) {
            int chunk = tid + it * 256;           // 1024 chunks of 8 bf16
            int row = chunk >> 3, c8 = (chunk & 7) * 8;
            *reinterpret_cast<uint4*>(&As[row * 72 + c8]) =
                *reinterpret_cast<const uint4*>(&A[(size_t)(m0 + row) * KDIM + k0 + c8]);
            *reinterpret_cast<uint4*>(&Bs[row * 72 + c8]) =
                *reinterpret_cast<const uint4*>(&Bm[(size_t)(n0 + row) * KDIM + k0 + c8]);
        }
        __syncthreads();
        #pragma unroll
        for (int kk = 0; kk < 2; ++kk) {
            bf16x8 af[4], bg[4];
            #pragma unroll
            for (int i = 0; i < 4; ++i) {
                af[i] = *reinterpret_cast<const bf16x8*>(&As[(wm*64 + i*16 + qm)*72 + kk*32 + qk*8]);
                bg[i] = *reinterpret_cast<const bf16x8*>(&Bs[(wn*64 + i*16 + qm)*72 + kk*32 + qk*8]);
            }
            #pragma unroll
            for (int i = 0; i < 4; ++i)
                #pragma unroll
                for (int j = 0; j < 4; ++j)
                    acc[i][j] = __builtin_amdgcn_mfma_f32_16x16x32_bf16(af[i], bg[j], acc[i][j], 0, 0, 0);
        }
        __syncthreads();
    }
    // C/D layout: col = lane&15, row = (lane>>4)*4 + reg  [m89/m91-verified]
    #pragma unroll
    for (int i = 0; i < 4; ++i) {
        const int r0 = m0 + wm*64 + i*16 + qk*4;
        #pragma unroll
        for (int j = 0; j < 4; ++j) {
            const int c = n0 + wn*64 + j*16 + qm;
            const float bv = bias[c];
            if (MODE == 0) {
                #pragma unroll
                for (int reg = 0; reg < 4; ++reg)
                    out[(size_t)(r0 + reg) * D_MODEL + c] = acc[i][j][reg] + bv;
            } else {
                const int bb = r0 >> 12;           // batch
                const int l  = r0 & (SEQ - 1);     // 4 consecutive l -> float4
                float4 v = make_float4(acc[i][j][0] + bv, acc[i][j][1] + bv,
                                       acc[i][j][2] + bv, acc[i][j][3] + bv);
                *reinterpret_cast<float4*>(&out[((size_t)(bb * D_MODEL + c)) * SEQ + l]) = v;
            }
        }
    }
}

// ---------------------------------------------------------------------------
// scan: per-channel SSM recurrence, chunked (T=64), 16-chunk segments.
// One wave per (b,d). In-place: u_t -> y_t. Lane is both state idx n and
// within-chunk time t.
//   y[cT+t] = sum_{j<=t} k[t-j]u[cT+j] + sum_n C_n r_n^{t+1} h_n(cT-1) + Dp u
//   h <- r^64 h + dB * sum_j r^{63-j} u[j]   (Horner)
// ---------------------------------------------------------------------------
__global__ __launch_bounds__(64) void scan_kernel(
    float* __restrict__ ut, const float* __restrict__ A_log,
    const float* __restrict__ Bp, const float* __restrict__ Cp,
    const float* __restrict__ Dpv, const float* __restrict__ dtp)
{
    __shared__ float P2[64 * 68];   // P2[t][n] = C_n r_n^{t+1}
    __shared__ float Hs[16 * 68];   // chunk-boundary states for one segment
    __shared__ float u_sh[1024];
    __shared__ float k_pad[128];    // [0..63]=0, [64+m]=k[m]
    __shared__ float dB_sh[64], w_sh[64];

    const int ch = blockIdx.x;          // b*1024 + d
    const int d  = ch & (D_MODEL - 1);
    const int lane = threadIdx.x;

    const float dt_d = dtp[d];
    const float a    = A_log[d * D_STATE + lane];
    const float logdA = -expf(-a) * dt_d;
    const float r   = expf(logdA);
    const float rT  = expf(logdA * 64.0f);
    const float dBv = Bp[d * D_STATE + lane] * dt_d;
    const float Cv  = Cp[d * D_STATE + lane];
    const float Dpd = Dpv[d];

    {   // build P2 (lane = n writes column n)
        float p = Cv;
        for (int t = 0; t < 64; ++t) { p *= r; P2[t * 68 + lane] = p; }
        dB_sh[lane] = dBv;
        w_sh[lane]  = Cv * dBv;
    }
    __syncthreads();
    {   // build k[m] = sum_n C dB r^m ; note P2[m-1][n] = C_n r_n^m
        float kacc = 0.f;
        const int mm = (lane == 0) ? 0 : (lane - 1);
        for (int n = 0; n < 64; ++n) {
            float t1 = (lane == 0) ? w_sh[n] : dB_sh[n] * P2[mm * 68 + n];
            kacc += t1;
        }
        k_pad[lane] = 0.f;
        k_pad[64 + lane] = kacc;
    }
    __syncthreads();

    float h = 0.f;
    float* ug = ut + (size_t)ch * SEQ;
    for (int seg = 0; seg < 4; ++seg) {
        __syncthreads();
        #pragma unroll
        for (int i2 = 0; i2 < 4; ++i2) {
            float4 v = *reinterpret_cast<const float4*>(&ug[seg * 1024 + i2 * 256 + lane * 4]);
            *reinterpret_cast<float4*>(&u_sh[i2 * 256 + lane * 4]) = v;
        }
        __syncthreads();

        float yc[16], s[16];
        #pragma unroll
        for (int c = 0; c < 16; ++c) { yc[c] = 0.f; s[c] = 0.f; }

        for (int jj = 0; jj < 16; ++jj) {           // j = 4*jj .. 4*jj+3 within chunk
            const int j0 = jj * 4;
            const int kb = 64 + lane - j0;
            const float k0v = k_pad[kb],     k1v = k_pad[kb - 1];
            const float k2v = k_pad[kb - 2], k3v = k_pad[kb - 3];
            #pragma unroll
            for (int c = 0; c < 16; ++c) {
                float4 u4 = *reinterpret_cast<const float4*>(&u_sh[c * 64 + j0]);
                yc[c] += k0v * u4.x + k1v * u4.y + k2v * u4.z + k3v * u4.w;
                s[c] = (((s[c] * r + u4.x) * r + u4.y) * r + u4.z) * r + u4.w;
            }
        }
        // chunk-boundary states (lane = n)
        #pragma unroll
        for (int c = 0; c < 16; ++c) {
            Hs[c * 68 + lane] = h;
            h = rT * h + dBv * s[c];
        }
        __syncthreads();
        // state contribution (lane = t)
        float yst[16];
        #pragma unroll
        for (int c = 0; c < 16; ++c) yst[c] = 0.f;
        for (int n0 = 0; n0 < 16; ++n0) {
            float4 p4 = *reinterpret_cast<const float4*>(&P2[lane * 68 + n0 * 4]);
            #pragma unroll
            for (int c = 0; c < 16; ++c) {
                float4 h4 = *reinterpret_cast<const float4*>(&Hs[c * 68 + n0 * 4]);
                yst[c] += p4.x * h4.x + p4.y * h4.y + p4.z * h4.z + p4.w * h4.w;
            }
        }
        __syncthreads();
        #pragma unroll
        for (int c = 0; c < 16; ++c) {
            float y = yc[c] + yst[c] + Dpd * u_sh[c * 64 + lane];
            ug[seg * 1024 + c * 64 + lane] = y;     // in-place over u
        }
    }
}

// ---------------------------------------------------------------------------
// transpose y_t[b][d][l] fp32 -> A rows [b*L][2048] hi|lo bf16 for GEMM2.
// 64(d) x 64(l) LDS tile.
// ---------------------------------------------------------------------------
__global__ __launch_bounds__(256) void trans_kernel(
    const float* __restrict__ yt, u16* __restrict__ Ax)
{
    __shared__ float T[64 * 68];
    const int b = blockIdx.z, dx = blockIdx.y * 64, lx = blockIdx.x * 64;
    const int tid = threadIdx.x;
    const int t16 = tid >> 4, l16 = tid & 15;
    #pragma unroll
    for (int ii = 0; ii < 4; ++ii) {
        const int dd = ii * 16 + t16;
        const int ll = l16 * 4;
        float4 v = *reinterpret_cast<const float4*>(
            &yt[((size_t)(b * D_MODEL + dx + dd)) * SEQ + lx + ll]);
        *reinterpret_cast<float4*>(&T[dd * 68 + ll]) = v;
    }
    __syncthreads();
    #pragma unroll
    for (int ii = 0; ii < 4; ++ii) {
        const int ll = ii * 16 + t16;   // l within tile
        const int dd = l16 * 4;         // d group
        float v0 = T[(dd + 0) * 68 + ll], v1 = T[(dd + 1) * 68 + ll];
        float v2 = T[(dd + 2) * 68 + ll], v3 = T[(dd + 3) * 68 + ll];
        u16 h0 = f2bf(v0), h1 = f2bf(v1), h2 = f2bf(v2), h3 = f2bf(v3);
        u16 l0 = f2bf(v0 - bf2f(h0)), l1 = f2bf(v1 - bf2f(h1));
        u16 l2 = f2bf(v2 - bf2f(h2)), l3 = f2bf(v3 - bf2f(h3));
        const size_t row = (size_t)b * SEQ + lx + ll;
        *reinterpret_cast<uint2*>(Ax + row * KDIM + dx + dd) =
            make_uint2((u32)h0 | ((u32)h1 << 16), (u32)h2 | ((u32)h3 << 16));
        *reinterpret_cast<uint2*>(Ax + row * KDIM + D_MODEL + dx + dd) =
            make_uint2((u32)l0 | ((u32)l1 << 16), (u32)l2 | ((u32)l3 << 16));
    }
}

// ---------------------------------------------------------------------------
// Workspace layout (needs 75,497,472 B):
//   [0,  32MB)  Ax   : activation hi|lo bf16 (in_proj input, then out_proj input)
//   [32, 64MB)  u_t  : [b][d][l] fp32 (scan in-place -> y_t)
//   [64, 68MB)  Bw1  : [Win|Win] bf16
//   [68, 72MB)  Bw2  : [Wout|Wout] bf16
// ---------------------------------------------------------------------------
extern "C" void kernel_launch(void* const* d_in, const int* in_sizes, int n_in,
                              void* d_out, int out_size, void* d_ws, size_t ws_size,
                              hipStream_t stream) {
    const float* x     = (const float*)d_in[0];
    const float* Win   = (const float*)d_in[1];
    const float* bin   = (const float*)d_in[2];
    const float* A_log = (const float*)d_in[3];
    const float* Bp    = (const float*)d_in[4];
    const float* Cp    = (const float*)d_in[5];
    const float* Dpv   = (const float*)d_in[6];
    const float* dtp   = (const float*)d_in[7];
    const float* Wout  = (const float*)d_in[8];
    const float* bout  = (const float*)d_in[9];
    float* out = (float*)d_out;

    char* ws = (char*)d_ws;
    u16*   Ax  = (u16*)(ws);
    float* ut  = (float*)(ws + (size_t)33554432);
    u16*   Bw1 = (u16*)(ws + (size_t)67108864);
    u16*   Bw2 = (u16*)(ws + (size_t)71303168);

    prep_kernel<<<MROWS + 2 * D_MODEL, 256, 0, stream>>>(x, Win, Wout, Ax, Bw1, Bw2);
    gemm_bt<1><<<dim3(D_MODEL / 128, MROWS / 128), 256, 0, stream>>>(Ax, Bw1, bin, ut);
    scan_kernel<<<BATCH * D_MODEL, 64, 0, stream>>>(ut, A_log, Bp, Cp, Dpv, dtp);
    trans_kernel<<<dim3(SEQ / 64, D_MODEL / 64, BATCH), 256, 0, stream>>>(ut, Ax);
    gemm_bt<0><<<dim3(D_MODEL / 128, MROWS / 128), 256, 0, stream>>>(Ax, Bw2, bout, out);
}

// Round 2
// 255.754 us; speedup vs baseline: 1.2795x; 1.2795x over previous
//
#include <hip/hip_runtime.h>
#include <cstdint>
#include <cstddef>

#define D_MODEL 1024
#define D_STATE 64
#define SEQ     4096
#define BATCH   2
#define MROWS   (BATCH*SEQ)   // 8192 rows of activations
#define KDIM    (2*D_MODEL)   // 2048: hi|lo split K

typedef __bf16 bf16x8 __attribute__((ext_vector_type(8)));
typedef float  f32x4  __attribute__((ext_vector_type(4)));
typedef unsigned short u16;
typedef unsigned int   u32;

union BF8 { bf16x8 v; uint4 q; u16 e[8]; };

__device__ __forceinline__ u16 f2bf(float x) {
    u32 u = __float_as_uint(x);
    u32 r = u + 0x7FFFu + ((u >> 16) & 1u);   // RNE on bf16 boundary
    return (u16)(r >> 16);
}
__device__ __forceinline__ float bf2f(u16 h) {
    return __uint_as_float(((u32)h) << 16);
}
__device__ __forceinline__ uint4 pack8u(const u16* e) {
    return make_uint4((u32)e[0] | ((u32)e[1] << 16), (u32)e[2] | ((u32)e[3] << 16),
                      (u32)e[4] | ((u32)e[5] << 16), (u32)e[6] | ((u32)e[7] << 16));
}

// ---------------------------------------------------------------------------
// prep: x -> Ax (hi|lo bf16, [8192][2048]); Win -> Bw1; Wout -> Bw2.
// ---------------------------------------------------------------------------
__global__ __launch_bounds__(256) void prep_kernel(
    const float* __restrict__ x, const float* __restrict__ Win,
    const float* __restrict__ Wout,
    u16* __restrict__ Ax, u16* __restrict__ Bw1, u16* __restrict__ Bw2)
{
    const int blk = blockIdx.x, tid = threadIdx.x;
    const int k = tid * 4;
    if (blk < MROWS) {
        const float4 v = *reinterpret_cast<const float4*>(x + (size_t)blk * D_MODEL + k);
        u16 h0 = f2bf(v.x), h1 = f2bf(v.y), h2 = f2bf(v.z), h3 = f2bf(v.w);
        u16 l0 = f2bf(v.x - bf2f(h0)), l1 = f2bf(v.y - bf2f(h1));
        u16 l2 = f2bf(v.z - bf2f(h2)), l3 = f2bf(v.w - bf2f(h3));
        *reinterpret_cast<uint2*>(Ax + (size_t)blk * KDIM + k) =
            make_uint2((u32)h0 | ((u32)h1 << 16), (u32)h2 | ((u32)h3 << 16));
        *reinterpret_cast<uint2*>(Ax + (size_t)blk * KDIM + D_MODEL + k) =
            make_uint2((u32)l0 | ((u32)l1 << 16), (u32)l2 | ((u32)l3 << 16));
    } else if (blk < MROWS + D_MODEL) {
        const int row = blk - MROWS;
        const float4 v = *reinterpret_cast<const float4*>(Win + (size_t)row * D_MODEL + k);
        u32 w0 = (u32)f2bf(v.x) | ((u32)f2bf(v.y) << 16);
        u32 w1 = (u32)f2bf(v.z) | ((u32)f2bf(v.w) << 16);
        *reinterpret_cast<uint2*>(Bw1 + (size_t)row * KDIM + k) = make_uint2(w0, w1);
        *reinterpret_cast<uint2*>(Bw1 + (size_t)row * KDIM + D_MODEL + k) = make_uint2(w0, w1);
    } else {
        const int row = blk - MROWS - D_MODEL;
        const float4 v = *reinterpret_cast<const float4*>(Wout + (size_t)row * D_MODEL + k);
        u32 w0 = (u32)f2bf(v.x) | ((u32)f2bf(v.y) << 16);
        u32 w1 = (u32)f2bf(v.z) | ((u32)f2bf(v.w) << 16);
        *reinterpret_cast<uint2*>(Bw2 + (size_t)row * KDIM + k) = make_uint2(w0, w1);
        *reinterpret_cast<uint2*>(Bw2 + (size_t)row * KDIM + D_MODEL + k) = make_uint2(w0, w1);
    }
}

// ---------------------------------------------------------------------------
// gemm_bt: out[m,c] = sum_k A[m,k]*Bm[c,k] + bias[c].  (unchanged from R1)
// ---------------------------------------------------------------------------
template<int MODE>
__global__ __launch_bounds__(256) void gemm_bt(
    const u16* __restrict__ A, const u16* __restrict__ Bm,
    const float* __restrict__ bias, float* __restrict__ out)
{
    __shared__ u16 As[128 * 72];
    __shared__ u16 Bs[128 * 72];
    const int m0 = blockIdx.y * 128, n0 = blockIdx.x * 128;
    const int tid = threadIdx.x;
    const int wave = tid >> 6, lane = tid & 63;
    const int wm = wave >> 1, wn = wave & 1;
    const int qm = lane & 15, qk = lane >> 4;
    f32x4 acc[4][4] = {};
    for (int k0 = 0; k0 < KDIM; k0 += 64) {
        #pragma unroll
        for (int it = 0; it < 4; ++it) {
            int chunk = tid + it * 256;
            int row = chunk >> 3, c8 = (chunk & 7) * 8;
            *reinterpret_cast<uint4*>(&As[row * 72 + c8]) =
                *reinterpret_cast<const uint4*>(&A[(size_t)(m0 + row) * KDIM + k0 + c8]);
            *reinterpret_cast<uint4*>(&Bs[row * 72 + c8]) =
                *reinterpret_cast<const uint4*>(&Bm[(size_t)(n0 + row) * KDIM + k0 + c8]);
        }
        __syncthreads();
        #pragma unroll
        for (int kk = 0; kk < 2; ++kk) {
            bf16x8 af[4], bg[4];
            #pragma unroll
            for (int i = 0; i < 4; ++i) {
                af[i] = *reinterpret_cast<const bf16x8*>(&As[(wm*64 + i*16 + qm)*72 + kk*32 + qk*8]);
                bg[i] = *reinterpret_cast<const bf16x8*>(&Bs[(wn*64 + i*16 + qm)*72 + kk*32 + qk*8]);
            }
            #pragma unroll
            for (int i = 0; i < 4; ++i)
                #pragma unroll
                for (int j = 0; j < 4; ++j)
                    acc[i][j] = __builtin_amdgcn_mfma_f32_16x16x32_bf16(af[i], bg[j], acc[i][j], 0, 0, 0);
        }
        __syncthreads();
    }
    #pragma unroll
    for (int i = 0; i < 4; ++i) {
        const int r0 = m0 + wm*64 + i*16 + qk*4;
        #pragma unroll
        for (int j = 0; j < 4; ++j) {
            const int c = n0 + wn*64 + j*16 + qm;
            const float bv = bias[c];
            if (MODE == 0) {
                #pragma unroll
                for (int reg = 0; reg < 4; ++reg)
                    out[(size_t)(r0 + reg) * D_MODEL + c] = acc[i][j][reg] + bv;
            } else {
                const int bb = r0 >> 12;
                const int l  = r0 & (SEQ - 1);
                float4 v = make_float4(acc[i][j][0] + bv, acc[i][j][1] + bv,
                                       acc[i][j][2] + bv, acc[i][j][3] + bv);
                *reinterpret_cast<float4*>(&out[((size_t)(bb * D_MODEL + c)) * SEQ + l]) = v;
            }
        }
    }
}

// ---------------------------------------------------------------------------
// prep2: per-d SSM tables (bf16) into Tg blob [d][ KT(64x64) | RA(64x64) | P2(64x64) ]
//   KT[t][j] = k[t-j] (j<=t), k[m] = sum_n C_n dB_n r_n^m   (NO Dp fold; skip is exact fp32)
//   RA[n][j] = r_n^(63-j)
//   P2[t][n] = C_n r_n^(t+1)
// 1024 blocks x 64 threads.
// ---------------------------------------------------------------------------
__global__ __launch_bounds__(64) void prep2_kernel(
    const float* __restrict__ A_log, const float* __restrict__ Bp,
    const float* __restrict__ Cp, const float* __restrict__ dtp,
    u16* __restrict__ Tg)
{
    __shared__ float P[64 * 65];   // stride 65 -> conflict-free row reads
    __shared__ float k_sh[64];
    const int d = blockIdx.x, lane = threadIdx.x;
    const float dt_d  = dtp[d];
    const float logdA = -expf(-A_log[d * D_STATE + lane]) * dt_d;
    const float r     = expf(logdA);
    const float dBn   = Bp[d * D_STATE + lane] * dt_d;
    const float Cv    = Cp[d * D_STATE + lane];
    u16* tg = Tg + (size_t)d * 12288;

    // ---- P2: lane=n builds column, lane=t writes row
    {
        float p = Cv;
        for (int t = 0; t < 64; ++t) { p *= r; P[t * 65 + lane] = p; }
    }
    __syncthreads();
    {
        const int t = lane;
        for (int o = 0; o < 8; ++o) {
            u16 e[8];
            #pragma unroll
            for (int i = 0; i < 8; ++i) e[i] = f2bf(P[t * 65 + o * 8 + i]);
            *reinterpret_cast<uint4*>(&tg[8192 + t * 64 + o * 8]) = pack8u(e);
        }
    }
    __syncthreads();
    // ---- k[m]: P[m][n] = C dB r^m, then cross-n sum with lane=m
    {
        float p = Cv * dBn;
        for (int m = 0; m < 64; ++m) { P[m * 65 + lane] = p; p *= r; }
    }
    __syncthreads();
    {
        float kacc = 0.f;
        for (int n = 0; n < 64; ++n) kacc += P[lane * 65 + n];
        k_sh[lane] = kacc;
    }
    __syncthreads();
    {   // KT rows, lane=t
        const int t = lane;
        for (int o = 0; o < 8; ++o) {
            u16 e[8];
            #pragma unroll
            for (int i = 0; i < 8; ++i) {
                const int j = o * 8 + i;
                e[i] = (j <= t) ? f2bf(k_sh[t - j]) : (u16)0;
            }
            *reinterpret_cast<uint4*>(&tg[t * 64 + o * 8]) = pack8u(e);
        }
    }
    // ---- RA rows, lane=n: r^(63-j), j ascending (exp descending; build octet backward)
    {
        for (int o = 0; o < 8; ++o) {
            float tmp[8];
            tmp[7] = expf(logdA * (float)(63 - (o * 8 + 7)));
            #pragma unroll
            for (int i = 6; i >= 0; --i) tmp[i] = tmp[i + 1] * r;
            u16 e[8];
            #pragma unroll
            for (int i = 0; i < 8; ++i) e[i] = f2bf(tmp[i]);
            *reinterpret_cast<uint4*>(&tg[4096 + lane * 64 + o * 8]) = pack8u(e);
        }
    }
}

// ---------------------------------------------------------------------------
// scan2: MFMA chunked scan. 1024 blocks (one per d) x 128 thr (wave w = batch w).
// Per wave (channel = (b,d)), chunks c=0..63 of T=64, u hi/lo split (K=128):
//   S[n][c]  = RA_ext @ U_ext          (64 MFMA)
//   serial:  H[c]=h; h = rT*h + dB*S[c]   (lane=n, in-place in SH)
//   Y[t][c]  = KT_ext @ U_ext + P2 @ H  (96 MFMA)
//   y = Y + Dp*u (u re-read fp32), stored in-place over ut.
// Fragment conventions identical to gemm_bt (HW-verified in R1).
// ---------------------------------------------------------------------------
__global__ __launch_bounds__(128) void scan2_kernel(
    float* __restrict__ ut, const float* __restrict__ A_log,
    const float* __restrict__ Bp, const float* __restrict__ dtp,
    const float* __restrict__ Dpv, const u16* __restrict__ Tg)
{
    __shared__ u16 KT_s[64 * 72];
    __shared__ u16 RA_s[64 * 72];
    __shared__ u16 P2_s[64 * 72];
    __shared__ u16 SH[2][64 * 72];   // per-wave S then H, [c][n], 72-stride (16B-aligned rows)
    const int d = blockIdx.x, tid = threadIdx.x;
    const int w = tid >> 6, lane = tid & 63;
    const int qm = lane & 15, qk = lane >> 4;

    // stage the 3 per-d tables (24 KB) global -> LDS, shared by both waves
    const u16* tg = Tg + (size_t)d * 12288;
    #pragma unroll
    for (int it = 0; it < 12; ++it) {
        const int q = tid + it * 128;          // uint4 index 0..1535
        const int row = q >> 3, c8 = (q & 7) * 8;
        u16* dst = (row < 64)  ? &KT_s[row * 72 + c8]
                 : (row < 128) ? &RA_s[(row - 64) * 72 + c8]
                               : &P2_s[(row - 128) * 72 + c8];
        *reinterpret_cast<uint4*>(dst) =
            *reinterpret_cast<const uint4*>(&tg[row * 64 + c8]);
    }

    // per-lane (n-role) params
    const float dt_d  = dtp[d];
    const float logdA = -expf(-A_log[d * D_STATE + lane]) * dt_d;
    const float dBn   = Bp[d * D_STATE + lane] * dt_d;
    const float rTn   = expf(logdA * 64.0f);
    const float Dpd   = Dpv[d];

    float* ug = ut + ((size_t)(w * D_MODEL + d)) * SEQ;

    // U B-fragments in registers: Uf[ct][kk], kk 0..1 = hi(j 0..63), 2..3 = lo
    bf16x8 Uf[4][4];
    #pragma unroll
    for (int ct = 0; ct < 4; ++ct) {
        const float* src = ug + (ct * 16 + qm) * 64;
        #pragma unroll
        for (int jb = 0; jb < 2; ++jb) {
            const float4 v0 = *reinterpret_cast<const float4*>(src + jb * 32 + qk * 8);
            const float4 v1 = *reinterpret_cast<const float4*>(src + jb * 32 + qk * 8 + 4);
            const float fv[8] = {v0.x, v0.y, v0.z, v0.w, v1.x, v1.y, v1.z, v1.w};
            BF8 hi, lo;
            #pragma unroll
            for (int i = 0; i < 8; ++i) {
                hi.e[i] = f2bf(fv[i]);
                lo.e[i] = f2bf(fv[i] - bf2f(hi.e[i]));
            }
            Uf[ct][jb]     = hi.v;
            Uf[ct][jb + 2] = lo.v;
        }
    }
    __syncthreads();

    u16* sh = SH[w];
    {   // ---- S = RA_ext @ U_ext -> SH[c][n] bf16
        bf16x8 Af[4][2];
        #pragma unroll
        for (int nt = 0; nt < 4; ++nt)
            #pragma unroll
            for (int jb = 0; jb < 2; ++jb)
                Af[nt][jb] = *reinterpret_cast<const bf16x8*>(
                    &RA_s[(nt * 16 + qm) * 72 + jb * 32 + qk * 8]);
        f32x4 acc[4][4] = {};
        #pragma unroll
        for (int kk = 0; kk < 4; ++kk)
            #pragma unroll
            for (int nt = 0; nt < 4; ++nt)
                #pragma unroll
                for (int ct = 0; ct < 4; ++ct)
                    acc[nt][ct] = __builtin_amdgcn_mfma_f32_16x16x32_bf16(
                        Af[nt][kk & 1], Uf[ct][kk], acc[nt][ct], 0, 0, 0);
        #pragma unroll
        for (int nt = 0; nt < 4; ++nt)
            #pragma unroll
            for (int ct = 0; ct < 4; ++ct) {
                const int c = ct * 16 + qm, n0 = nt * 16 + qk * 4;
                uint2 pk;
                pk.x = (u32)f2bf(acc[nt][ct][0]) | ((u32)f2bf(acc[nt][ct][1]) << 16);
                pk.y = (u32)f2bf(acc[nt][ct][2]) | ((u32)f2bf(acc[nt][ct][3]) << 16);
                *reinterpret_cast<uint2*>(&sh[c * 72 + n0]) = pk;
            }
    }
    __syncthreads();

    {   // ---- serial inter-chunk state hop, lane = n; SH: S[c] read -> H[c] written
        float h = 0.f;
        for (int c = 0; c < 64; ++c) {
            const float s = bf2f(sh[c * 72 + lane]);
            sh[c * 72 + lane] = f2bf(h);          // state ENTERING chunk c
            h = rTn * h + dBn * s;
        }
    }
    __syncthreads();

    {   // ---- Y = KT_ext @ U_ext + P2 @ H ; epilogue adds Dp*u (fp32) in-place
        bf16x8 Af[4][2];
        #pragma unroll
        for (int tt = 0; tt < 4; ++tt)
            #pragma unroll
            for (int jb = 0; jb < 2; ++jb)
                Af[tt][jb] = *reinterpret_cast<const bf16x8*>(
                    &KT_s[(tt * 16 + qm) * 72 + jb * 32 + qk * 8]);
        f32x4 acc[4][4] = {};
        #pragma unroll
        for (int kk = 0; kk < 4; ++kk)
            #pragma unroll
            for (int tt = 0; tt < 4; ++tt)
                #pragma unroll
                for (int ct = 0; ct < 4; ++ct)
                    acc[tt][ct] = __builtin_amdgcn_mfma_f32_16x16x32_bf16(
                        Af[tt][kk & 1], Uf[ct][kk], acc[tt][ct], 0, 0, 0);
        bf16x8 Pf[4][2];
        #pragma unroll
        for (int tt = 0; tt < 4; ++tt)
            #pragma unroll
            for (int kb = 0; kb < 2; ++kb)
                Pf[tt][kb] = *reinterpret_cast<const bf16x8*>(
                    &P2_s[(tt * 16 + qm) * 72 + kb * 32 + qk * 8]);
        #pragma unroll
        for (int ct = 0; ct < 4; ++ct)
            #pragma unroll
            for (int kb = 0; kb < 2; ++kb) {
                const bf16x8 Hf = *reinterpret_cast<const bf16x8*>(
                    &sh[(ct * 16 + qm) * 72 + kb * 32 + qk * 8]);
                #pragma unroll
                for (int tt = 0; tt < 4; ++tt)
                    acc[tt][ct] = __builtin_amdgcn_mfma_f32_16x16x32_bf16(
                        Pf[tt][kb], Hf, acc[tt][ct], 0, 0, 0);
            }
        #pragma unroll
        for (int tt = 0; tt < 4; ++tt)
            #pragma unroll
            for (int ct = 0; ct < 4; ++ct) {
                const int c = ct * 16 + qm, t0 = tt * 16 + qk * 4;
                float* dst = ug + c * 64 + t0;
                const float4 u4 = *reinterpret_cast<const float4*>(dst);
                float4 y;
                y.x = acc[tt][ct][0] + Dpd * u4.x;
                y.y = acc[tt][ct][1] + Dpd * u4.y;
                y.z = acc[tt][ct][2] + Dpd * u4.z;
                y.w = acc[tt][ct][3] + Dpd * u4.w;
                *reinterpret_cast<float4*>(dst) = y;
            }
    }
}

// ---------------------------------------------------------------------------
// transpose y_t[b][d][l] fp32 -> Ax rows [b*L][2048] hi|lo bf16 for GEMM2.
// ---------------------------------------------------------------------------
__global__ __launch_bounds__(256) void trans_kernel(
    const float* __restrict__ yt, u16* __restrict__ Ax)
{
    __shared__ float T[64 * 68];
    const int b = blockIdx.z, dx = blockIdx.y * 64, lx = blockIdx.x * 64;
    const int tid = threadIdx.x;
    const int t16 = tid >> 4, l16 = tid & 15;
    #pragma unroll
    for (int ii = 0; ii < 4; ++ii) {
        const int dd = ii * 16 + t16;
        const int ll = l16 * 4;
        float4 v = *reinterpret_cast<const float4*>(
            &yt[((size_t)(b * D_MODEL + dx + dd)) * SEQ + lx + ll]);
        *reinterpret_cast<float4*>(&T[dd * 68 + ll]) = v;
    }
    __syncthreads();
    #pragma unroll
    for (int ii = 0; ii < 4; ++ii) {
        const int ll = ii * 16 + t16;
        const int dd = l16 * 4;
        float v0 = T[(dd + 0) * 68 + ll], v1 = T[(dd + 1) * 68 + ll];
        float v2 = T[(dd + 2) * 68 + ll], v3 = T[(dd + 3) * 68 + ll];
        u16 h0 = f2bf(v0), h1 = f2bf(v1), h2 = f2bf(v2), h3 = f2bf(v3);
        u16 l0 = f2bf(v0 - bf2f(h0)), l1 = f2bf(v1 - bf2f(h1));
        u16 l2 = f2bf(v2 - bf2f(h2)), l3 = f2bf(v3 - bf2f(h3));
        const size_t row = (size_t)b * SEQ + lx + ll;
        *reinterpret_cast<uint2*>(Ax + row * KDIM + dx + dd) =
            make_uint2((u32)h0 | ((u32)h1 << 16), (u32)h2 | ((u32)h3 << 16));
        *reinterpret_cast<uint2*>(Ax + row * KDIM + D_MODEL + dx + dd) =
            make_uint2((u32)l0 | ((u32)l1 << 16), (u32)l2 | ((u32)l3 << 16));
    }
}

// ---------------------------------------------------------------------------
// Workspace (75.5 MB, same as R1):
//   [0,  32MB)  Ax   : activation hi|lo bf16. ALSO hosts Tg tables (24MB) during
//                      the scan phase (Ax is dead between gemm1 and trans).
//   [32, 64MB)  ut   : [b][d][l] fp32 (scan in-place -> y_t)
//   [64, 68MB)  Bw1  : [Win|Win] bf16
//   [68, 72MB)  Bw2  : [Wout|Wout] bf16
// Order: prep -> gemm1(reads Ax) -> prep2(writes tables over Ax) -> scan2
//        -> trans(rewrites Ax) -> gemm2. Stream-ordered, graph-capture safe.
// ---------------------------------------------------------------------------
extern "C" void kernel_launch(void* const* d_in, const int* in_sizes, int n_in,
                              void* d_out, int out_size, void* d_ws, size_t ws_size,
                              hipStream_t stream) {
    const float* x     = (const float*)d_in[0];
    const float* Win   = (const float*)d_in[1];
    const float* bin   = (const float*)d_in[2];
    const float* A_log = (const float*)d_in[3];
    const float* Bp    = (const float*)d_in[4];
    const float* Cp    = (const float*)d_in[5];
    const float* Dpv   = (const float*)d_in[6];
    const float* dtp   = (const float*)d_in[7];
    const float* Wout  = (const float*)d_in[8];
    const float* bout  = (const float*)d_in[9];
    float* out = (float*)d_out;

    char* ws = (char*)d_ws;
    u16*   Ax  = (u16*)(ws);
    u16*   Tg  = (u16*)(ws);                          // aliases Ax (phase-disjoint)
    float* ut  = (float*)(ws + (size_t)33554432);
    u16*   Bw1 = (u16*)(ws + (size_t)67108864);
    u16*   Bw2 = (u16*)(ws + (size_t)71303168);

    prep_kernel<<<MROWS + 2 * D_MODEL, 256, 0, stream>>>(x, Win, Wout, Ax, Bw1, Bw2);
    gemm_bt<1><<<dim3(D_MODEL / 128, MROWS / 128), 256, 0, stream>>>(Ax, Bw1, bin, ut);
    prep2_kernel<<<D_MODEL, 64, 0, stream>>>(A_log, Bp, Cp, dtp, Tg);
    scan2_kernel<<<D_MODEL, 128, 0, stream>>>(ut, A_log, Bp, dtp, Dpv, Tg);
    trans_kernel<<<dim3(SEQ / 64, D_MODEL / 64, BATCH), 256, 0, stream>>>(ut, Ax);
    gemm_bt<0><<<dim3(D_MODEL / 128, MROWS / 128), 256, 0, stream>>>(Ax, Bw2, bout, out);
}

// Round 3
// 218.976 us; speedup vs baseline: 1.4944x; 1.1680x over previous
//
#include <hip/hip_runtime.h>
#include <cstdint>
#include <cstddef>

#define D_MODEL 1024
#define D_STATE 64
#define SEQ     4096
#define BATCH   2
#define MROWS   (BATCH*SEQ)   // 8192 rows of activations

typedef __bf16 bf16x8 __attribute__((ext_vector_type(8)));
typedef float  f32x4  __attribute__((ext_vector_type(4)));
typedef unsigned short u16;
typedef unsigned int   u32;

union BF8 { bf16x8 v; uint4 q; u16 e[8]; };

__device__ __forceinline__ u16 f2bf(float x) {
    u32 u = __float_as_uint(x);
    u32 r = u + 0x7FFFu + ((u >> 16) & 1u);   // RNE on bf16 boundary
    return (u16)(r >> 16);
}
__device__ __forceinline__ float bf2f(u16 h) {
    return __uint_as_float(((u32)h) << 16);
}
__device__ __forceinline__ uint4 pack8u(const u16* e) {
    return make_uint4((u32)e[0] | ((u32)e[1] << 16), (u32)e[2] | ((u32)e[3] << 16),
                      (u32)e[4] | ((u32)e[5] << 16), (u32)e[6] | ((u32)e[7] << 16));
}

// async global->LDS, 16B per lane. LDS dest is wave-uniform base + lane*16
// (m104/m108) — caller passes the wave-uniform base; global addr is per-lane.
__device__ __forceinline__ void async16(const void* g, void* l) {
    __builtin_amdgcn_global_load_lds(
        (const __attribute__((address_space(1))) unsigned int*)(uintptr_t)g,
        (__attribute__((address_space(3))) unsigned int*)(uintptr_t)l,
        16, 0, 0);
}

// ---------------------------------------------------------------------------
// prep: x -> Ax (bf16 [8192][1024]); Win -> Bw1 (bf16); Wout -> Bw2 (bf16).
// ---------------------------------------------------------------------------
__global__ __launch_bounds__(256) void prep_kernel(
    const float* __restrict__ x, const float* __restrict__ Win,
    const float* __restrict__ Wout,
    u16* __restrict__ Ax, u16* __restrict__ Bw1, u16* __restrict__ Bw2)
{
    const int blk = blockIdx.x, tid = threadIdx.x;
    const int k = tid * 4;
    const float* src; u16* dst; int row;
    if (blk < MROWS)                  { src = x;    dst = Ax;  row = blk; }
    else if (blk < MROWS + D_MODEL)   { src = Win;  dst = Bw1; row = blk - MROWS; }
    else                              { src = Wout; dst = Bw2; row = blk - MROWS - D_MODEL; }
    const float4 v = *reinterpret_cast<const float4*>(src + (size_t)row * D_MODEL + k);
    *reinterpret_cast<uint2*>(dst + (size_t)row * D_MODEL + k) =
        make_uint2((u32)f2bf(v.x) | ((u32)f2bf(v.y) << 16),
                   (u32)f2bf(v.z) | ((u32)f2bf(v.w) << 16));
}

// ---------------------------------------------------------------------------
// gemm_bt: out[m,c] = sum_k A[m,k]*Bm[c,k] + bias[c], K=1024 plain bf16.
// 128x128 tile, 4 waves (2x2 of 64x64), BK=64, mfma 16x16x32 bf16.
// m97-style staging: global_load_lds width=16 into UNPADDED stride-64 LDS.
// MODE 0: fp32 [m][1024] store (out_proj). MODE 1: transposed into ut[b][c][l].
// ---------------------------------------------------------------------------
template<int MODE>
__global__ __launch_bounds__(256) void gemm_bt(
    const u16* __restrict__ A, const u16* __restrict__ Bm,
    const float* __restrict__ bias, float* __restrict__ out)
{
    __shared__ u16 As[128 * 64];   // unpadded: global_load_lds needs lane-linear dest
    __shared__ u16 Bs[128 * 64];
    const int m0 = blockIdx.y * 128, n0 = blockIdx.x * 128;
    const int tid = threadIdx.x;
    const int wave = tid >> 6, lane = tid & 63;
    const int wm = wave >> 1, wn = wave & 1;
    const int qm = lane & 15, qk = lane >> 4;
    f32x4 acc[4][4] = {};
    for (int k0 = 0; k0 < D_MODEL; k0 += 64) {
        #pragma unroll
        for (int it = 0; it < 4; ++it) {
            const int c   = it * 256 + tid;          // chunk 0..1023 (16B each)
            const int row = c >> 3, col = (c & 7) * 8;
            const int ldsbase = (it * 256 + wave * 64) * 8;   // wave-uniform, elems
            async16(&A[(size_t)(m0 + row) * D_MODEL + k0 + col], &As[ldsbase]);
            async16(&Bm[(size_t)(n0 + row) * D_MODEL + k0 + col], &Bs[ldsbase]);
        }
        __syncthreads();
        #pragma unroll
        for (int kk = 0; kk < 2; ++kk) {
            bf16x8 af[4], bg[4];
            #pragma unroll
            for (int i = 0; i < 4; ++i) {
                af[i] = *reinterpret_cast<const bf16x8*>(&As[(wm*64 + i*16 + qm)*64 + kk*32 + qk*8]);
                bg[i] = *reinterpret_cast<const bf16x8*>(&Bs[(wn*64 + i*16 + qm)*64 + kk*32 + qk*8]);
            }
            #pragma unroll
            for (int i = 0; i < 4; ++i)
                #pragma unroll
                for (int j = 0; j < 4; ++j)
                    acc[i][j] = __builtin_amdgcn_mfma_f32_16x16x32_bf16(af[i], bg[j], acc[i][j], 0, 0, 0);
        }
        __syncthreads();
    }
    // C/D layout: col = lane&15, row = (lane>>4)*4 + reg  [m89/m91-verified]
    #pragma unroll
    for (int i = 0; i < 4; ++i) {
        const int r0 = m0 + wm*64 + i*16 + qk*4;
        #pragma unroll
        for (int j = 0; j < 4; ++j) {
            const int c = n0 + wn*64 + j*16 + qm;
            const float bv = bias[c];
            if (MODE == 0) {
                #pragma unroll
                for (int reg = 0; reg < 4; ++reg)
                    out[(size_t)(r0 + reg) * D_MODEL + c] = acc[i][j][reg] + bv;
            } else {
                const int bb = r0 >> 12;
                const int l  = r0 & (SEQ - 1);
                float4 v = make_float4(acc[i][j][0] + bv, acc[i][j][1] + bv,
                                       acc[i][j][2] + bv, acc[i][j][3] + bv);
                *reinterpret_cast<float4*>(&out[((size_t)(bb * D_MODEL + c)) * SEQ + l]) = v;
            }
        }
    }
}

// ---------------------------------------------------------------------------
// prep2: per-d SSM tables (bf16) into Tg blob [d][ KT | RA | P2 ] (64x64 each)
//   KT[t][j] = k[t-j] (j<=t), k[m] = sum_n C_n dB_n r_n^m
//   RA[n][j] = r_n^(63-j)
//   P2[t][n] = C_n r_n^(t+1)
// ---------------------------------------------------------------------------
__global__ __launch_bounds__(64) void prep2_kernel(
    const float* __restrict__ A_log, const float* __restrict__ Bp,
    const float* __restrict__ Cp, const float* __restrict__ dtp,
    u16* __restrict__ Tg)
{
    __shared__ float P[64 * 65];
    __shared__ float k_sh[64];
    const int d = blockIdx.x, lane = threadIdx.x;
    const float dt_d  = dtp[d];
    const float logdA = -expf(-A_log[d * D_STATE + lane]) * dt_d;
    const float r     = expf(logdA);
    const float dBn   = Bp[d * D_STATE + lane] * dt_d;
    const float Cv    = Cp[d * D_STATE + lane];
    u16* tg = Tg + (size_t)d * 12288;

    {   // P2: lane=n builds column, lane=t writes row
        float p = Cv;
        for (int t = 0; t < 64; ++t) { p *= r; P[t * 65 + lane] = p; }
    }
    __syncthreads();
    {
        const int t = lane;
        for (int o = 0; o < 8; ++o) {
            u16 e[8];
            #pragma unroll
            for (int i = 0; i < 8; ++i) e[i] = f2bf(P[t * 65 + o * 8 + i]);
            *reinterpret_cast<uint4*>(&tg[8192 + t * 64 + o * 8]) = pack8u(e);
        }
    }
    __syncthreads();
    {   // k[m]: P[m][n] = C dB r^m, cross-n sum with lane=m
        float p = Cv * dBn;
        for (int m = 0; m < 64; ++m) { P[m * 65 + lane] = p; p *= r; }
    }
    __syncthreads();
    {
        float kacc = 0.f;
        for (int n = 0; n < 64; ++n) kacc += P[lane * 65 + n];
        k_sh[lane] = kacc;
    }
    __syncthreads();
    {   // KT rows, lane=t
        const int t = lane;
        for (int o = 0; o < 8; ++o) {
            u16 e[8];
            #pragma unroll
            for (int i = 0; i < 8; ++i) {
                const int j = o * 8 + i;
                e[i] = (j <= t) ? f2bf(k_sh[t - j]) : (u16)0;
            }
            *reinterpret_cast<uint4*>(&tg[t * 64 + o * 8]) = pack8u(e);
        }
    }
    {   // RA rows, lane=n
        for (int o = 0; o < 8; ++o) {
            float tmp[8];
            tmp[7] = expf(logdA * (float)(63 - (o * 8 + 7)));
            #pragma unroll
            for (int i = 6; i >= 0; --i) tmp[i] = tmp[i + 1] * r;
            u16 e[8];
            #pragma unroll
            for (int i = 0; i < 8; ++i) e[i] = f2bf(tmp[i]);
            *reinterpret_cast<uint4*>(&tg[4096 + lane * 64 + o * 8]) = pack8u(e);
        }
    }
}

// ---------------------------------------------------------------------------
// scan2: MFMA chunked scan (unchanged from R2 — verified). 1024 blocks x 128 thr.
// ---------------------------------------------------------------------------
__global__ __launch_bounds__(128) void scan2_kernel(
    float* __restrict__ ut, const float* __restrict__ A_log,
    const float* __restrict__ Bp, const float* __restrict__ dtp,
    const float* __restrict__ Dpv, const u16* __restrict__ Tg)
{
    __shared__ u16 KT_s[64 * 72];
    __shared__ u16 RA_s[64 * 72];
    __shared__ u16 P2_s[64 * 72];
    __shared__ u16 SH[2][64 * 72];
    const int d = blockIdx.x, tid = threadIdx.x;
    const int w = tid >> 6, lane = tid & 63;
    const int qm = lane & 15, qk = lane >> 4;

    const u16* tg = Tg + (size_t)d * 12288;
    #pragma unroll
    for (int it = 0; it < 12; ++it) {
        const int q = tid + it * 128;
        const int row = q >> 3, c8 = (q & 7) * 8;
        u16* dst = (row < 64)  ? &KT_s[row * 72 + c8]
                 : (row < 128) ? &RA_s[(row - 64) * 72 + c8]
                               : &P2_s[(row - 128) * 72 + c8];
        *reinterpret_cast<uint4*>(dst) =
            *reinterpret_cast<const uint4*>(&tg[row * 64 + c8]);
    }

    const float dt_d  = dtp[d];
    const float logdA = -expf(-A_log[d * D_STATE + lane]) * dt_d;
    const float dBn   = Bp[d * D_STATE + lane] * dt_d;
    const float rTn   = expf(logdA * 64.0f);
    const float Dpd   = Dpv[d];

    float* ug = ut + ((size_t)(w * D_MODEL + d)) * SEQ;

    bf16x8 Uf[4][4];
    #pragma unroll
    for (int ct = 0; ct < 4; ++ct) {
        const float* src = ug + (ct * 16 + qm) * 64;
        #pragma unroll
        for (int jb = 0; jb < 2; ++jb) {
            const float4 v0 = *reinterpret_cast<const float4*>(src + jb * 32 + qk * 8);
            const float4 v1 = *reinterpret_cast<const float4*>(src + jb * 32 + qk * 8 + 4);
            const float fv[8] = {v0.x, v0.y, v0.z, v0.w, v1.x, v1.y, v1.z, v1.w};
            BF8 hi, lo;
            #pragma unroll
            for (int i = 0; i < 8; ++i) {
                hi.e[i] = f2bf(fv[i]);
                lo.e[i] = f2bf(fv[i] - bf2f(hi.e[i]));
            }
            Uf[ct][jb]     = hi.v;
            Uf[ct][jb + 2] = lo.v;
        }
    }
    __syncthreads();

    u16* sh = SH[w];
    {   // S = RA_ext @ U_ext -> SH[c][n] bf16
        bf16x8 Af[4][2];
        #pragma unroll
        for (int nt = 0; nt < 4; ++nt)
            #pragma unroll
            for (int jb = 0; jb < 2; ++jb)
                Af[nt][jb] = *reinterpret_cast<const bf16x8*>(
                    &RA_s[(nt * 16 + qm) * 72 + jb * 32 + qk * 8]);
        f32x4 acc[4][4] = {};
        #pragma unroll
        for (int kk = 0; kk < 4; ++kk)
            #pragma unroll
            for (int nt = 0; nt < 4; ++nt)
                #pragma unroll
                for (int ct = 0; ct < 4; ++ct)
                    acc[nt][ct] = __builtin_amdgcn_mfma_f32_16x16x32_bf16(
                        Af[nt][kk & 1], Uf[ct][kk], acc[nt][ct], 0, 0, 0);
        #pragma unroll
        for (int nt = 0; nt < 4; ++nt)
            #pragma unroll
            for (int ct = 0; ct < 4; ++ct) {
                const int c = ct * 16 + qm, nn0 = nt * 16 + qk * 4;
                uint2 pk;
                pk.x = (u32)f2bf(acc[nt][ct][0]) | ((u32)f2bf(acc[nt][ct][1]) << 16);
                pk.y = (u32)f2bf(acc[nt][ct][2]) | ((u32)f2bf(acc[nt][ct][3]) << 16);
                *reinterpret_cast<uint2*>(&sh[c * 72 + nn0]) = pk;
            }
    }
    __syncthreads();

    {   // serial inter-chunk state hop, lane=n
        float h = 0.f;
        for (int c = 0; c < 64; ++c) {
            const float s = bf2f(sh[c * 72 + lane]);
            sh[c * 72 + lane] = f2bf(h);
            h = rTn * h + dBn * s;
        }
    }
    __syncthreads();

    {   // Y = KT_ext @ U_ext + P2 @ H ; epilogue adds Dp*u in fp32, in-place
        bf16x8 Af[4][2];
        #pragma unroll
        for (int tt = 0; tt < 4; ++tt)
            #pragma unroll
            for (int jb = 0; jb < 2; ++jb)
                Af[tt][jb] = *reinterpret_cast<const bf16x8*>(
                    &KT_s[(tt * 16 + qm) * 72 + jb * 32 + qk * 8]);
        f32x4 acc[4][4] = {};
        #pragma unroll
        for (int kk = 0; kk < 4; ++kk)
            #pragma unroll
            for (int tt = 0; tt < 4; ++tt)
                #pragma unroll
                for (int ct = 0; ct < 4; ++ct)
                    acc[tt][ct] = __builtin_amdgcn_mfma_f32_16x16x32_bf16(
                        Af[tt][kk & 1], Uf[ct][kk], acc[tt][ct], 0, 0, 0);
        bf16x8 Pf[4][2];
        #pragma unroll
        for (int tt = 0; tt < 4; ++tt)
            #pragma unroll
            for (int kb = 0; kb < 2; ++kb)
                Pf[tt][kb] = *reinterpret_cast<const bf16x8*>(
                    &P2_s[(tt * 16 + qm) * 72 + kb * 32 + qk * 8]);
        #pragma unroll
        for (int ct = 0; ct < 4; ++ct)
            #pragma unroll
            for (int kb = 0; kb < 2; ++kb) {
                const bf16x8 Hf = *reinterpret_cast<const bf16x8*>(
                    &sh[(ct * 16 + qm) * 72 + kb * 32 + qk * 8]);
                #pragma unroll
                for (int tt = 0; tt < 4; ++tt)
                    acc[tt][ct] = __builtin_amdgcn_mfma_f32_16x16x32_bf16(
                        Pf[tt][kb], Hf, acc[tt][ct], 0, 0, 0);
            }
        #pragma unroll
        for (int tt = 0; tt < 4; ++tt)
            #pragma unroll
            for (int ct = 0; ct < 4; ++ct) {
                const int c = ct * 16 + qm, t0 = tt * 16 + qk * 4;
                float* dst = ug + c * 64 + t0;
                const float4 u4 = *reinterpret_cast<const float4*>(dst);
                float4 y;
                y.x = acc[tt][ct][0] + Dpd * u4.x;
                y.y = acc[tt][ct][1] + Dpd * u4.y;
                y.z = acc[tt][ct][2] + Dpd * u4.z;
                y.w = acc[tt][ct][3] + Dpd * u4.w;
                *reinterpret_cast<float4*>(dst) = y;
            }
    }
}

// ---------------------------------------------------------------------------
// transpose y_t[b][d][l] fp32 -> Ax rows [b*L][1024] bf16 for GEMM2.
// ---------------------------------------------------------------------------
__global__ __launch_bounds__(256) void trans_kernel(
    const float* __restrict__ yt, u16* __restrict__ Ax)
{
    __shared__ float T[64 * 68];
    const int b = blockIdx.z, dx = blockIdx.y * 64, lx = blockIdx.x * 64;
    const int tid = threadIdx.x;
    const int t16 = tid >> 4, l16 = tid & 15;
    #pragma unroll
    for (int ii = 0; ii < 4; ++ii) {
        const int dd = ii * 16 + t16;
        const int ll = l16 * 4;
        float4 v = *reinterpret_cast<const float4*>(
            &yt[((size_t)(b * D_MODEL + dx + dd)) * SEQ + lx + ll]);
        *reinterpret_cast<float4*>(&T[dd * 68 + ll]) = v;
    }
    __syncthreads();
    #pragma unroll
    for (int ii = 0; ii < 4; ++ii) {
        const int ll = ii * 16 + t16;
        const int dd = l16 * 4;
        float v0 = T[(dd + 0) * 68 + ll], v1 = T[(dd + 1) * 68 + ll];
        float v2 = T[(dd + 2) * 68 + ll], v3 = T[(dd + 3) * 68 + ll];
        const size_t row = (size_t)b * SEQ + lx + ll;
        *reinterpret_cast<uint2*>(Ax + row * D_MODEL + dx + dd) =
            make_uint2((u32)f2bf(v0) | ((u32)f2bf(v1) << 16),
                       (u32)f2bf(v2) | ((u32)f2bf(v3) << 16));
    }
}

// ---------------------------------------------------------------------------
// Workspace (60 MB):
//   [0,  24MB)  Ax (16MB used) / Tg tables (24MB) — phase-disjoint alias
//   [24, 56MB)  ut : [b][d][l] fp32 (scan in-place -> y_t)
//   [56, 58MB)  Bw1 : Win bf16
//   [58, 60MB)  Bw2 : Wout bf16
// Order: prep -> gemm1(reads Ax) -> prep2(Tg over Ax) -> scan2
//        -> trans(rewrites Ax) -> gemm2.
// ---------------------------------------------------------------------------
extern "C" void kernel_launch(void* const* d_in, const int* in_sizes, int n_in,
                              void* d_out, int out_size, void* d_ws, size_t ws_size,
                              hipStream_t stream) {
    const float* x     = (const float*)d_in[0];
    const float* Win   = (const float*)d_in[1];
    const float* bin   = (const float*)d_in[2];
    const float* A_log = (const float*)d_in[3];
    const float* Bp    = (const float*)d_in[4];
    const float* Cp    = (const float*)d_in[5];
    const float* Dpv   = (const float*)d_in[6];
    const float* dtp   = (const float*)d_in[7];
    const float* Wout  = (const float*)d_in[8];
    const float* bout  = (const float*)d_in[9];
    float* out = (float*)d_out;

    char* ws = (char*)d_ws;
    u16*   Ax  = (u16*)(ws);
    u16*   Tg  = (u16*)(ws);                          // aliases Ax (phase-disjoint)
    float* ut  = (float*)(ws + (size_t)25165824);
    u16*   Bw1 = (u16*)(ws + (size_t)58720256);
    u16*   Bw2 = (u16*)(ws + (size_t)60817408);

    prep_kernel<<<MROWS + 2 * D_MODEL, 256, 0, stream>>>(x, Win, Wout, Ax, Bw1, Bw2);
    gemm_bt<1><<<dim3(D_MODEL / 128, MROWS / 128), 256, 0, stream>>>(Ax, Bw1, bin, ut);
    prep2_kernel<<<D_MODEL, 64, 0, stream>>>(A_log, Bp, Cp, dtp, Tg);
    scan2_kernel<<<D_MODEL, 128, 0, stream>>>(ut, A_log, Bp, dtp, Dpv, Tg);
    trans_kernel<<<dim3(SEQ / 64, D_MODEL / 64, BATCH), 256, 0, stream>>>(ut, Ax);
    gemm_bt<0><<<dim3(D_MODEL / 128, MROWS / 128), 256, 0, stream>>>(Ax, Bw2, bout, out);
}

// Round 4
// 199.146 us; speedup vs baseline: 1.6432x; 1.0996x over previous
//
#include <hip/hip_runtime.h>
#include <cstdint>
#include <cstddef>

#define D_MODEL 1024
#define D_STATE 64
#define SEQ     4096
#define BATCH   2
#define MROWS   (BATCH*SEQ)   // 8192 rows of activations

typedef __bf16 bf16x8 __attribute__((ext_vector_type(8)));
typedef float  f32x4  __attribute__((ext_vector_type(4)));
typedef unsigned short u16;
typedef unsigned int   u32;

union BF8 { bf16x8 v; uint4 q; u16 e[8]; };

__device__ __forceinline__ u16 f2bf(float x) {
    u32 u = __float_as_uint(x);
    u32 r = u + 0x7FFFu + ((u >> 16) & 1u);   // RNE on bf16 boundary
    return (u16)(r >> 16);
}
__device__ __forceinline__ float bf2f(u16 h) {
    return __uint_as_float(((u32)h) << 16);
}
__device__ __forceinline__ uint4 pack8u(const u16* e) {
    return make_uint4((u32)e[0] | ((u32)e[1] << 16), (u32)e[2] | ((u32)e[3] << 16),
                      (u32)e[4] | ((u32)e[5] << 16), (u32)e[6] | ((u32)e[7] << 16));
}

// async global->LDS, 16B per lane. LDS dest is wave-uniform base + lane*16.
__device__ __forceinline__ void async16(const void* g, void* l) {
    __builtin_amdgcn_global_load_lds(
        (const __attribute__((address_space(1))) unsigned int*)(uintptr_t)g,
        (__attribute__((address_space(3))) unsigned int*)(uintptr_t)l,
        16, 0, 0);
}

// ---------------------------------------------------------------------------
// prep: x -> Ax (bf16 [8192][1024]); Win -> Bw1 (bf16); Wout -> Bw2 (bf16).
// ---------------------------------------------------------------------------
__global__ __launch_bounds__(256) void prep_kernel(
    const float* __restrict__ x, const float* __restrict__ Win,
    const float* __restrict__ Wout,
    u16* __restrict__ Ax, u16* __restrict__ Bw1, u16* __restrict__ Bw2)
{
    const int blk = blockIdx.x, tid = threadIdx.x;
    const int k = tid * 4;
    const float* src; u16* dst; int row;
    if (blk < MROWS)                  { src = x;    dst = Ax;  row = blk; }
    else if (blk < MROWS + D_MODEL)   { src = Win;  dst = Bw1; row = blk - MROWS; }
    else                              { src = Wout; dst = Bw2; row = blk - MROWS - D_MODEL; }
    const float4 v = *reinterpret_cast<const float4*>(src + (size_t)row * D_MODEL + k);
    *reinterpret_cast<uint2*>(dst + (size_t)row * D_MODEL + k) =
        make_uint2((u32)f2bf(v.x) | ((u32)f2bf(v.y) << 16),
                   (u32)f2bf(v.z) | ((u32)f2bf(v.w) << 16));
}

// ---------------------------------------------------------------------------
// gemm_bt: out[m,c] = sum_k A[m,k]*Bm[c,k] + bias[c], K=1024 bf16.
// 128x128 tile, 4 waves (2x2 of 64x64), BK=64, mfma 16x16x32 bf16,
// global_load_lds width=16 staging (m97 structure).
// MODE 0: fp32 [m][1024] coalesced store (out_proj).
// MODE 1: transposed store into ut[b][c][l] via per-wave LDS patch ->
//         each lane emits 64B-dense dwordx4 runs along l (no write amplification).
// ---------------------------------------------------------------------------
template<int MODE>
__global__ __launch_bounds__(256) void gemm_bt(
    const u16* __restrict__ A, const u16* __restrict__ Bm,
    const float* __restrict__ bias, float* __restrict__ out)
{
    __shared__ u16 As[128 * 64];   // unpadded: global_load_lds is lane-linear
    __shared__ u16 Bs[128 * 64];
    __shared__ float Tt[MODE == 1 ? 4 * 16 * 65 : 4];   // per-wave transpose patch
    const int m0 = blockIdx.y * 128, n0 = blockIdx.x * 128;
    const int tid = threadIdx.x;
    const int wave = tid >> 6, lane = tid & 63;
    const int wm = wave >> 1, wn = wave & 1;
    const int qm = lane & 15, qk = lane >> 4;
    f32x4 acc[4][4] = {};
    for (int k0 = 0; k0 < D_MODEL; k0 += 64) {
        #pragma unroll
        for (int it = 0; it < 4; ++it) {
            const int c   = it * 256 + tid;          // chunk 0..1023 (16B each)
            const int row = c >> 3, col = (c & 7) * 8;
            const int ldsbase = (it * 256 + wave * 64) * 8;   // wave-uniform, elems
            async16(&A[(size_t)(m0 + row) * D_MODEL + k0 + col], &As[ldsbase]);
            async16(&Bm[(size_t)(n0 + row) * D_MODEL + k0 + col], &Bs[ldsbase]);
        }
        __syncthreads();
        #pragma unroll
        for (int kk = 0; kk < 2; ++kk) {
            bf16x8 af[4], bg[4];
            #pragma unroll
            for (int i = 0; i < 4; ++i) {
                af[i] = *reinterpret_cast<const bf16x8*>(&As[(wm*64 + i*16 + qm)*64 + kk*32 + qk*8]);
                bg[i] = *reinterpret_cast<const bf16x8*>(&Bs[(wn*64 + i*16 + qm)*64 + kk*32 + qk*8]);
            }
            #pragma unroll
            for (int i = 0; i < 4; ++i)
                #pragma unroll
                for (int j = 0; j < 4; ++j)
                    acc[i][j] = __builtin_amdgcn_mfma_f32_16x16x32_bf16(af[i], bg[j], acc[i][j], 0, 0, 0);
        }
        __syncthreads();
    }
    // C/D layout: col = lane&15, row = (lane>>4)*4 + reg  [m89/m91-verified]
    if (MODE == 0) {
        #pragma unroll
        for (int i = 0; i < 4; ++i) {
            const int r0 = m0 + wm*64 + i*16 + qk*4;
            #pragma unroll
            for (int j = 0; j < 4; ++j) {
                const int c = n0 + wn*64 + j*16 + qm;
                const float bv = bias[c];
                #pragma unroll
                for (int reg = 0; reg < 4; ++reg)
                    out[(size_t)(r0 + reg) * D_MODEL + c] = acc[i][j][reg] + bv;
            }
        }
    } else {
        float* T = &Tt[wave * 16 * 65];
        float bvj[4];
        #pragma unroll
        for (int j = 0; j < 4; ++j) bvj[j] = bias[n0 + wn*64 + j*16 + qm];
        const int dcol = n0 + wn*64 + lane;            // read-phase column (d)
        #pragma unroll
        for (int i = 0; i < 4; ++i) {
            // write 16(l) x 64(d) strip into patch
            #pragma unroll
            for (int j = 0; j < 4; ++j)
                #pragma unroll
                for (int reg = 0; reg < 4; ++reg)
                    T[(qk*4 + reg) * 65 + j*16 + qm] = acc[i][j][reg] + bvj[j];
            __builtin_amdgcn_wave_barrier();
            // read back: one d per lane, 16 contiguous l -> 4 dense dwordx4
            float4 o[4];
            #pragma unroll
            for (int t4 = 0; t4 < 4; ++t4)
                o[t4] = make_float4(T[(t4*4 + 0) * 65 + lane], T[(t4*4 + 1) * 65 + lane],
                                    T[(t4*4 + 2) * 65 + lane], T[(t4*4 + 3) * 65 + lane]);
            const int r0 = m0 + wm*64 + i*16;          // 16 l values, same batch
            const int bb = r0 >> 12, l0 = r0 & (SEQ - 1);
            float* dst = &out[((size_t)(bb * D_MODEL + dcol)) * SEQ + l0];
            #pragma unroll
            for (int t4 = 0; t4 < 4; ++t4)
                reinterpret_cast<float4*>(dst)[t4] = o[t4];
            __builtin_amdgcn_wave_barrier();
        }
    }
}

// ---------------------------------------------------------------------------
// scan2: MFMA chunked scan WITH fused in-LDS table build (prep2 absorbed).
// 1024 blocks (one per d) x 128 thr (wave w = batch w).
// Tables (bf16, built per block):
//   KT[t][j] = k[t-j] (j<=t), k[m] = sum_n C_n dB_n r_n^m   (wave0)
//   RA[n][j] = r_n^(63-j), P2[t][n] = C_n r_n^(t+1)          (wave1)
// Then per wave: S = RA@U_ext; serial hop h=rT*h+dB*S; Y = KT@U_ext + P2@H;
// y = Y + Dp*u (fp32), in-place over ut.
// ---------------------------------------------------------------------------
__global__ __launch_bounds__(128) void scan2_kernel(
    float* __restrict__ ut, const float* __restrict__ A_log,
    const float* __restrict__ Bp, const float* __restrict__ Cp,
    const float* __restrict__ dtp, const float* __restrict__ Dpv)
{
    __shared__ u16 KT_s[64 * 72];
    __shared__ u16 RA_s[64 * 72];
    __shared__ u16 P2_s[64 * 72];
    __shared__ u16 SH[2][64 * 72];   // scratch during build; S/H per wave after
    const int d = blockIdx.x, tid = threadIdx.x;
    const int w = tid >> 6, lane = tid & 63;
    const int qm = lane & 15, qk = lane >> 4;

    const float dt_d  = dtp[d];
    const float logdA = -expf(-A_log[d * D_STATE + lane]) * dt_d;
    const float r     = expf(logdA);
    const float dBn   = Bp[d * D_STATE + lane] * dt_d;
    const float Cv    = Cp[d * D_STATE + lane];
    const float rTn   = expf(logdA * 64.0f);
    const float Dpd   = Dpv[d];

    float* ug = ut + ((size_t)(w * D_MODEL + d)) * SEQ;

    // ---- U B-fragments (global fp32 -> hi/lo bf16), kk 0..1 = hi, 2..3 = lo
    bf16x8 Uf[4][4];
    #pragma unroll
    for (int ct = 0; ct < 4; ++ct) {
        const float* src = ug + (ct * 16 + qm) * 64;
        #pragma unroll
        for (int jb = 0; jb < 2; ++jb) {
            const float4 v0 = *reinterpret_cast<const float4*>(src + jb * 32 + qk * 8);
            const float4 v1 = *reinterpret_cast<const float4*>(src + jb * 32 + qk * 8 + 4);
            const float fv[8] = {v0.x, v0.y, v0.z, v0.w, v1.x, v1.y, v1.z, v1.w};
            BF8 hi, lo;
            #pragma unroll
            for (int i = 0; i < 8; ++i) {
                hi.e[i] = f2bf(fv[i]);
                lo.e[i] = f2bf(fv[i] - bf2f(hi.e[i]));
            }
            Uf[ct][jb]     = hi.v;
            Uf[ct][jb + 2] = lo.v;
        }
    }

    // ---- in-LDS table build (wave-divergent, wave-uniform branch)
    if (w == 1) {
        {   // P2 column n=lane: C r^{t+1}
            float p = Cv;
            for (int t = 0; t < 64; ++t) { p *= r; P2_s[t * 72 + lane] = f2bf(p); }
        }
        {   // RA row n=lane: r^(63-j), j ascending
            for (int o = 0; o < 8; ++o) {
                float tmp[8];
                tmp[7] = expf(logdA * (float)(63 - (o * 8 + 7)));
                #pragma unroll
                for (int i = 6; i >= 0; --i) tmp[i] = tmp[i + 1] * r;
                u16 e[8];
                #pragma unroll
                for (int i = 0; i < 8; ++i) e[i] = f2bf(tmp[i]);
                *reinterpret_cast<uint4*>(&RA_s[lane * 72 + o * 8]) = pack8u(e);
            }
        }
    } else {
        // scratch in SH[0] (dead until S-phase): P[64][65] fp32 + k[64] fp32
        float* scr = reinterpret_cast<float*>(&SH[0][0]);
        float* ksh = scr + 64 * 65;
        {   // P[m][n=lane] = C dB r^m
            float p = Cv * dBn;
            for (int m = 0; m < 64; ++m) { scr[m * 65 + lane] = p; p *= r; }
        }
        {   // k[m=lane] = sum_n P[m][n]  (same-wave LDS ops are in-order)
            float kacc = 0.f;
            for (int n = 0; n < 64; ++n) kacc += scr[lane * 65 + n];
            ksh[lane] = kacc;
        }
        {   // KT row t=lane
            for (int o = 0; o < 8; ++o) {
                u16 e[8];
                #pragma unroll
                for (int i = 0; i < 8; ++i) {
                    const int j = o * 8 + i;
                    e[i] = (j <= lane) ? f2bf(ksh[lane - j]) : (u16)0;
                }
                *reinterpret_cast<uint4*>(&KT_s[lane * 72 + o * 8]) = pack8u(e);
            }
        }
    }
    __syncthreads();

    u16* sh = SH[w];
    {   // S = RA_ext @ U_ext -> SH[w][c][n] bf16
        bf16x8 Af[4][2];
        #pragma unroll
        for (int nt = 0; nt < 4; ++nt)
            #pragma unroll
            for (int jb = 0; jb < 2; ++jb)
                Af[nt][jb] = *reinterpret_cast<const bf16x8*>(
                    &RA_s[(nt * 16 + qm) * 72 + jb * 32 + qk * 8]);
        f32x4 acc[4][4] = {};
        #pragma unroll
        for (int kk = 0; kk < 4; ++kk)
            #pragma unroll
            for (int nt = 0; nt < 4; ++nt)
                #pragma unroll
                for (int ct = 0; ct < 4; ++ct)
                    acc[nt][ct] = __builtin_amdgcn_mfma_f32_16x16x32_bf16(
                        Af[nt][kk & 1], Uf[ct][kk], acc[nt][ct], 0, 0, 0);
        #pragma unroll
        for (int nt = 0; nt < 4; ++nt)
            #pragma unroll
            for (int ct = 0; ct < 4; ++ct) {
                const int c = ct * 16 + qm, nn0 = nt * 16 + qk * 4;
                uint2 pk;
                pk.x = (u32)f2bf(acc[nt][ct][0]) | ((u32)f2bf(acc[nt][ct][1]) << 16);
                pk.y = (u32)f2bf(acc[nt][ct][2]) | ((u32)f2bf(acc[nt][ct][3]) << 16);
                *reinterpret_cast<uint2*>(&sh[c * 72 + nn0]) = pk;
            }
    }
    __syncthreads();

    {   // serial inter-chunk state hop, lane=n
        float h = 0.f;
        for (int c = 0; c < 64; ++c) {
            const float s = bf2f(sh[c * 72 + lane]);
            sh[c * 72 + lane] = f2bf(h);
            h = rTn * h + dBn * s;
        }
    }
    __syncthreads();

    {   // Y = KT_ext @ U_ext + P2 @ H ; epilogue adds Dp*u in fp32, in-place
        bf16x8 Af[4][2];
        #pragma unroll
        for (int tt = 0; tt < 4; ++tt)
            #pragma unroll
            for (int jb = 0; jb < 2; ++jb)
                Af[tt][jb] = *reinterpret_cast<const bf16x8*>(
                    &KT_s[(tt * 16 + qm) * 72 + jb * 32 + qk * 8]);
        f32x4 acc[4][4] = {};
        #pragma unroll
        for (int kk = 0; kk < 4; ++kk)
            #pragma unroll
            for (int tt = 0; tt < 4; ++tt)
                #pragma unroll
                for (int ct = 0; ct < 4; ++ct)
                    acc[tt][ct] = __builtin_amdgcn_mfma_f32_16x16x32_bf16(
                        Af[tt][kk & 1], Uf[ct][kk], acc[tt][ct], 0, 0, 0);
        bf16x8 Pf[4][2];
        #pragma unroll
        for (int tt = 0; tt < 4; ++tt)
            #pragma unroll
            for (int kb = 0; kb < 2; ++kb)
                Pf[tt][kb] = *reinterpret_cast<const bf16x8*>(
                    &P2_s[(tt * 16 + qm) * 72 + kb * 32 + qk * 8]);
        #pragma unroll
        for (int ct = 0; ct < 4; ++ct)
            #pragma unroll
            for (int kb = 0; kb < 2; ++kb) {
                const bf16x8 Hf = *reinterpret_cast<const bf16x8*>(
                    &sh[(ct * 16 + qm) * 72 + kb * 32 + qk * 8]);
                #pragma unroll
                for (int tt = 0; tt < 4; ++tt)
                    acc[tt][ct] = __builtin_amdgcn_mfma_f32_16x16x32_bf16(
                        Pf[tt][kb], Hf, acc[tt][ct], 0, 0, 0);
            }
        #pragma unroll
        for (int tt = 0; tt < 4; ++tt)
            #pragma unroll
            for (int ct = 0; ct < 4; ++ct) {
                const int c = ct * 16 + qm, t0 = tt * 16 + qk * 4;
                float* dst = ug + c * 64 + t0;
                const float4 u4 = *reinterpret_cast<const float4*>(dst);
                float4 y;
                y.x = acc[tt][ct][0] + Dpd * u4.x;
                y.y = acc[tt][ct][1] + Dpd * u4.y;
                y.z = acc[tt][ct][2] + Dpd * u4.z;
                y.w = acc[tt][ct][3] + Dpd * u4.w;
                *reinterpret_cast<float4*>(dst) = y;
            }
    }
}

// ---------------------------------------------------------------------------
// transpose y_t[b][d][l] fp32 -> Ax rows [b*L][1024] bf16 for GEMM2.
// ---------------------------------------------------------------------------
__global__ __launch_bounds__(256) void trans_kernel(
    const float* __restrict__ yt, u16* __restrict__ Ax)
{
    __shared__ float T[64 * 68];
    const int b = blockIdx.z, dx = blockIdx.y * 64, lx = blockIdx.x * 64;
    const int tid = threadIdx.x;
    const int t16 = tid >> 4, l16 = tid & 15;
    #pragma unroll
    for (int ii = 0; ii < 4; ++ii) {
        const int dd = ii * 16 + t16;
        const int ll = l16 * 4;
        float4 v = *reinterpret_cast<const float4*>(
            &yt[((size_t)(b * D_MODEL + dx + dd)) * SEQ + lx + ll]);
        *reinterpret_cast<float4*>(&T[dd * 68 + ll]) = v;
    }
    __syncthreads();
    #pragma unroll
    for (int ii = 0; ii < 4; ++ii) {
        const int ll = ii * 16 + t16;
        const int dd = l16 * 4;
        float v0 = T[(dd + 0) * 68 + ll], v1 = T[(dd + 1) * 68 + ll];
        float v2 = T[(dd + 2) * 68 + ll], v3 = T[(dd + 3) * 68 + ll];
        const size_t row = (size_t)b * SEQ + lx + ll;
        *reinterpret_cast<uint2*>(Ax + row * D_MODEL + dx + dd) =
            make_uint2((u32)f2bf(v0) | ((u32)f2bf(v1) << 16),
                       (u32)f2bf(v2) | ((u32)f2bf(v3) << 16));
    }
}

// ---------------------------------------------------------------------------
// Workspace (60 MB):
//   [0,  24MB)  Ax (16MB used)
//   [24, 56MB)  ut : [b][d][l] fp32 (scan in-place -> y_t)
//   [56, 58MB)  Bw1 : Win bf16
//   [58, 60MB)  Bw2 : Wout bf16
// Order: prep -> gemm1(reads Ax, coalesced transposed store) -> scan2(fused
// tables) -> trans(rewrites Ax) -> gemm2.
// ---------------------------------------------------------------------------
extern "C" void kernel_launch(void* const* d_in, const int* in_sizes, int n_in,
                              void* d_out, int out_size, void* d_ws, size_t ws_size,
                              hipStream_t stream) {
    const float* x     = (const float*)d_in[0];
    const float* Win   = (const float*)d_in[1];
    const float* bin   = (const float*)d_in[2];
    const float* A_log = (const float*)d_in[3];
    const float* Bp    = (const float*)d_in[4];
    const float* Cp    = (const float*)d_in[5];
    const float* Dpv   = (const float*)d_in[6];
    const float* dtp   = (const float*)d_in[7];
    const float* Wout  = (const float*)d_in[8];
    const float* bout  = (const float*)d_in[9];
    float* out = (float*)d_out;

    char* ws = (char*)d_ws;
    u16*   Ax  = (u16*)(ws);
    float* ut  = (float*)(ws + (size_t)25165824);
    u16*   Bw1 = (u16*)(ws + (size_t)58720256);
    u16*   Bw2 = (u16*)(ws + (size_t)60817408);

    prep_kernel<<<MROWS + 2 * D_MODEL, 256, 0, stream>>>(x, Win, Wout, Ax, Bw1, Bw2);
    gemm_bt<1><<<dim3(D_MODEL / 128, MROWS / 128), 256, 0, stream>>>(Ax, Bw1, bin, ut);
    scan2_kernel<<<D_MODEL, 128, 0, stream>>>(ut, A_log, Bp, Cp, dtp, Dpv);
    trans_kernel<<<dim3(SEQ / 64, D_MODEL / 64, BATCH), 256, 0, stream>>>(ut, Ax);
    gemm_bt<0><<<dim3(D_MODEL / 128, MROWS / 128), 256, 0, stream>>>(Ax, Bw2, bout, out);
}

// Round 5
// 191.979 us; speedup vs baseline: 1.7045x; 1.0373x over previous
//
#include <hip/hip_runtime.h>
#include <cstdint>
#include <cstddef>

#define D_MODEL 1024
#define D_STATE 64
#define SEQ     4096
#define BATCH   2
#define MROWS   (BATCH*SEQ)   // 8192 rows of activations

typedef __bf16 bf16x8 __attribute__((ext_vector_type(8)));
typedef float  f32x4  __attribute__((ext_vector_type(4)));
typedef unsigned short u16;
typedef unsigned int   u32;

union BF8 { bf16x8 v; uint4 q; u16 e[8]; };

__device__ __forceinline__ u16 f2bf(float x) {
    u32 u = __float_as_uint(x);
    u32 r = u + 0x7FFFu + ((u >> 16) & 1u);   // RNE on bf16 boundary
    return (u16)(r >> 16);
}
__device__ __forceinline__ float bf2f(u16 h) {
    return __uint_as_float(((u32)h) << 16);
}
__device__ __forceinline__ uint4 pack8u(const u16* e) {
    return make_uint4((u32)e[0] | ((u32)e[1] << 16), (u32)e[2] | ((u32)e[3] << 16),
                      (u32)e[4] | ((u32)e[5] << 16), (u32)e[6] | ((u32)e[7] << 16));
}

// async global->LDS, 16B per lane. LDS dest is wave-uniform base + lane*16.
__device__ __forceinline__ void async16(const void* g, void* l) {
    __builtin_amdgcn_global_load_lds(
        (const __attribute__((address_space(1))) unsigned int*)(uintptr_t)g,
        (__attribute__((address_space(3))) unsigned int*)(uintptr_t)l,
        16, 0, 0);
}

// ---------------------------------------------------------------------------
// prep: x -> Ax (bf16 [8192][1024]); Win -> Bw1 (bf16); Wout -> Bw2 (bf16).
// ---------------------------------------------------------------------------
__global__ __launch_bounds__(256) void prep_kernel(
    const float* __restrict__ x, const float* __restrict__ Win,
    const float* __restrict__ Wout,
    u16* __restrict__ Ax, u16* __restrict__ Bw1, u16* __restrict__ Bw2)
{
    const int blk = blockIdx.x, tid = threadIdx.x;
    const int k = tid * 4;
    const float* src; u16* dst; int row;
    if (blk < MROWS)                  { src = x;    dst = Ax;  row = blk; }
    else if (blk < MROWS + D_MODEL)   { src = Win;  dst = Bw1; row = blk - MROWS; }
    else                              { src = Wout; dst = Bw2; row = blk - MROWS - D_MODEL; }
    const float4 v = *reinterpret_cast<const float4*>(src + (size_t)row * D_MODEL + k);
    *reinterpret_cast<uint2*>(dst + (size_t)row * D_MODEL + k) =
        make_uint2((u32)f2bf(v.x) | ((u32)f2bf(v.y) << 16),
                   (u32)f2bf(v.z) | ((u32)f2bf(v.w) << 16));
}

// ---------------------------------------------------------------------------
// gemm_bt: out[m,c] = sum_k A[m,k]*Bm[c,k] + bias[c], K=1024 bf16.
// 128x128 tile, 4 waves (2x2 of 64x64), BK=64, mfma 16x16x32 bf16.
// DOUBLE-BUFFERED global_load_lds staging: prefetch k+1 issued BEFORE compute
// of k, ONE barrier per K-iter (drain overlaps MFMA). 64 KB LDS, 2 blocks/CU
// (grid 512 = 2/CU anyway).
// MODE 0: fp32 [m][1024] coalesced store. MODE 1: transposed store into
// ut[b][c][l] via per-wave LDS patch (aliases As after last use).
// ---------------------------------------------------------------------------
template<int MODE>
__global__ __launch_bounds__(256) void gemm_bt(
    const u16* __restrict__ A, const u16* __restrict__ Bm,
    const float* __restrict__ bias, float* __restrict__ out)
{
    __shared__ __align__(16) u16 As[2][128 * 64];
    __shared__ __align__(16) u16 Bs[2][128 * 64];
    const int m0 = blockIdx.y * 128, n0 = blockIdx.x * 128;
    const int tid = threadIdx.x;
    const int wave = tid >> 6, lane = tid & 63;
    const int wm = wave >> 1, wn = wave & 1;
    const int qm = lane & 15, qk = lane >> 4;
    f32x4 acc[4][4] = {};

    auto stage = [&](u16* Ad, u16* Bd, int k0) {
        #pragma unroll
        for (int it = 0; it < 4; ++it) {
            const int c   = it * 256 + tid;          // chunk 0..1023 (16B each)
            const int row = c >> 3, col = (c & 7) * 8;
            const int ldsbase = (it * 256 + wave * 64) * 8;   // wave-uniform
            async16(&A[(size_t)(m0 + row) * D_MODEL + k0 + col], Ad + ldsbase);
            async16(&Bm[(size_t)(n0 + row) * D_MODEL + k0 + col], Bd + ldsbase);
        }
    };
    auto compute = [&](const u16* As_, const u16* Bs_) {
        #pragma unroll
        for (int kk = 0; kk < 2; ++kk) {
            bf16x8 af[4], bg[4];
            #pragma unroll
            for (int i = 0; i < 4; ++i) {
                af[i] = *reinterpret_cast<const bf16x8*>(&As_[(wm*64 + i*16 + qm)*64 + kk*32 + qk*8]);
                bg[i] = *reinterpret_cast<const bf16x8*>(&Bs_[(wn*64 + i*16 + qm)*64 + kk*32 + qk*8]);
            }
            #pragma unroll
            for (int i = 0; i < 4; ++i)
                #pragma unroll
                for (int j = 0; j < 4; ++j)
                    acc[i][j] = __builtin_amdgcn_mfma_f32_16x16x32_bf16(af[i], bg[j], acc[i][j], 0, 0, 0);
        }
    };

    stage(As[0], Bs[0], 0);
    __syncthreads();
    #pragma unroll 1
    for (int kp = 0; kp < 7; ++kp) {
        stage(As[1], Bs[1], 128 * kp + 64);
        compute(As[0], Bs[0]);
        __syncthreads();
        stage(As[0], Bs[0], 128 * kp + 128);
        compute(As[1], Bs[1]);
        __syncthreads();
    }
    stage(As[1], Bs[1], 960);
    compute(As[0], Bs[0]);      // k=896
    __syncthreads();
    compute(As[1], Bs[1]);      // k=960

    // C/D layout: col = lane&15, row = (lane>>4)*4 + reg  [m89/m91-verified]
    if (MODE == 0) {
        #pragma unroll
        for (int i = 0; i < 4; ++i) {
            const int r0 = m0 + wm*64 + i*16 + qk*4;
            #pragma unroll
            for (int j = 0; j < 4; ++j) {
                const int c = n0 + wn*64 + j*16 + qm;
                const float bv = bias[c];
                #pragma unroll
                for (int reg = 0; reg < 4; ++reg)
                    out[(size_t)(r0 + reg) * D_MODEL + c] = acc[i][j][reg] + bv;
            }
        }
    } else {
        // As[0] was last read in the compute before the final barrier; safe to
        // alias as the transpose patch after that barrier + final compute(As[1]).
        float* Tt = reinterpret_cast<float*>(&As[0][0]);   // 4 waves x 16x65 fp32
        float* T = &Tt[wave * 16 * 65];
        float bvj[4];
        #pragma unroll
        for (int j = 0; j < 4; ++j) bvj[j] = bias[n0 + wn*64 + j*16 + qm];
        const int dcol = n0 + wn*64 + lane;            // read-phase column (d)
        #pragma unroll
        for (int i = 0; i < 4; ++i) {
            #pragma unroll
            for (int j = 0; j < 4; ++j)
                #pragma unroll
                for (int reg = 0; reg < 4; ++reg)
                    T[(qk*4 + reg) * 65 + j*16 + qm] = acc[i][j][reg] + bvj[j];
            __builtin_amdgcn_wave_barrier();
            float4 o[4];
            #pragma unroll
            for (int t4 = 0; t4 < 4; ++t4)
                o[t4] = make_float4(T[(t4*4 + 0) * 65 + lane], T[(t4*4 + 1) * 65 + lane],
                                    T[(t4*4 + 2) * 65 + lane], T[(t4*4 + 3) * 65 + lane]);
            const int r0 = m0 + wm*64 + i*16;
            const int bb = r0 >> 12, l0 = r0 & (SEQ - 1);
            float* dst = &out[((size_t)(bb * D_MODEL + dcol)) * SEQ + l0];
            #pragma unroll
            for (int t4 = 0; t4 < 4; ++t4)
                reinterpret_cast<float4*>(dst)[t4] = o[t4];
            __builtin_amdgcn_wave_barrier();
        }
    }
}

// ---------------------------------------------------------------------------
// scan2: MFMA chunked scan, fused in-LDS table build. 1024 blocks x 128 thr.
// LDS = 5 x 64x64 u16 = 40960 B -> exactly 4 blocks/CU (matches grid 4/CU).
// Build: wave0 -> RA rows + dB/w scratch; wave1 -> P2 columns; sync;
//        wave0 -> k[m] from bf16 P2 (k[m]=sum_n dB_n P2[m-1][n]) -> KT rows.
// Then per wave: S = RA@U_ext; batched register hop; Y = KT@U_ext + P2@H;
// y = Y + Dp*u (fp32), in-place over ut.
// ---------------------------------------------------------------------------
__global__ __launch_bounds__(128) void scan2_kernel(
    float* __restrict__ ut, const float* __restrict__ A_log,
    const float* __restrict__ Bp, const float* __restrict__ Cp,
    const float* __restrict__ dtp, const float* __restrict__ Dpv)
{
    __shared__ __align__(16) u16 KT_s[64 * 64];
    __shared__ __align__(16) u16 RA_s[64 * 64];
    __shared__ __align__(16) u16 P2_s[64 * 64];
    __shared__ __align__(16) u16 SH[2][64 * 64];   // scratch during build; S/H after
    const int d = blockIdx.x, tid = threadIdx.x;
    const int w = tid >> 6, lane = tid & 63;
    const int qm = lane & 15, qk = lane >> 4;

    const float dt_d  = dtp[d];
    const float logdA = -expf(-A_log[d * D_STATE + lane]) * dt_d;
    const float r     = expf(logdA);
    const float dBn   = Bp[d * D_STATE + lane] * dt_d;
    const float Cv    = Cp[d * D_STATE + lane];
    const float rTn   = expf(logdA * 64.0f);
    const float Dpd   = Dpv[d];

    float* ug = ut + ((size_t)(w * D_MODEL + d)) * SEQ;

    // fp32 scratch inside SH (dead until S-phase): dB[64] | w[64] | k[64]
    float* dB_sh = reinterpret_cast<float*>(&SH[0][0]);
    float* w_sh  = dB_sh + 64;
    float* k_sh  = dB_sh + 128;

    // ---- U B-fragments (global fp32 -> hi/lo bf16), kk 0..1 = hi, 2..3 = lo
    bf16x8 Uf[4][4];
    #pragma unroll
    for (int ct = 0; ct < 4; ++ct) {
        const float* src = ug + (ct * 16 + qm) * 64;
        #pragma unroll
        for (int jb = 0; jb < 2; ++jb) {
            const float4 v0 = *reinterpret_cast<const float4*>(src + jb * 32 + qk * 8);
            const float4 v1 = *reinterpret_cast<const float4*>(src + jb * 32 + qk * 8 + 4);
            const float fv[8] = {v0.x, v0.y, v0.z, v0.w, v1.x, v1.y, v1.z, v1.w};
            BF8 hi, lo;
            #pragma unroll
            for (int i = 0; i < 8; ++i) {
                hi.e[i] = f2bf(fv[i]);
                lo.e[i] = f2bf(fv[i] - bf2f(hi.e[i]));
            }
            Uf[ct][jb]     = hi.v;
            Uf[ct][jb + 2] = lo.v;
        }
    }

    // ---- table build phase 1
    if (w == 0) {
        dB_sh[lane] = dBn;
        w_sh[lane]  = Cv * dBn;
        for (int o = 0; o < 8; ++o) {   // RA row n=lane: r^(63-j), j ascending
            float tmp[8];
            tmp[7] = expf(logdA * (float)(63 - (o * 8 + 7)));
            #pragma unroll
            for (int i = 6; i >= 0; --i) tmp[i] = tmp[i + 1] * r;
            u16 e[8];
            #pragma unroll
            for (int i = 0; i < 8; ++i) e[i] = f2bf(tmp[i]);
            *reinterpret_cast<uint4*>(&RA_s[lane * 64 + o * 8]) = pack8u(e);
        }
    } else {
        float p = Cv;                   // P2 column n=lane: C r^{t+1}
        for (int t = 0; t < 64; ++t) { p *= r; P2_s[t * 64 + lane] = f2bf(p); }
    }
    __syncthreads();
    // ---- table build phase 2 (wave0): k from P2, then KT rows
    if (w == 0) {
        float kacc = 0.f;
        if (lane == 0) {
            for (int n = 0; n < 64; ++n) kacc += w_sh[n];
        } else {
            const u16* prow = &P2_s[(lane - 1) * 64];
            for (int o = 0; o < 8; ++o) {
                BF8 p8; p8.q = *reinterpret_cast<const uint4*>(&prow[o * 8]);
                #pragma unroll
                for (int i = 0; i < 8; ++i) kacc += dB_sh[o * 8 + i] * bf2f(p8.e[i]);
            }
        }
        k_sh[lane] = kacc;              // same-wave LDS: in-order visibility
        for (int o = 0; o < 8; ++o) {   // KT row t=lane
            u16 e[8];
            #pragma unroll
            for (int i = 0; i < 8; ++i) {
                const int j = o * 8 + i;
                e[i] = (j <= lane) ? f2bf(k_sh[lane - j]) : (u16)0;
            }
            *reinterpret_cast<uint4*>(&KT_s[lane * 64 + o * 8]) = pack8u(e);
        }
    }
    __syncthreads();

    u16* sh = SH[w];
    {   // ---- S = RA_ext @ U_ext -> SH[w][c][n] bf16
        bf16x8 Af[4][2];
        #pragma unroll
        for (int nt = 0; nt < 4; ++nt)
            #pragma unroll
            for (int jb = 0; jb < 2; ++jb)
                Af[nt][jb] = *reinterpret_cast<const bf16x8*>(
                    &RA_s[(nt * 16 + qm) * 64 + jb * 32 + qk * 8]);
        f32x4 acc[4][4] = {};
        #pragma unroll
        for (int kk = 0; kk < 4; ++kk)
            #pragma unroll
            for (int nt = 0; nt < 4; ++nt)
                #pragma unroll
                for (int ct = 0; ct < 4; ++ct)
                    acc[nt][ct] = __builtin_amdgcn_mfma_f32_16x16x32_bf16(
                        Af[nt][kk & 1], Uf[ct][kk], acc[nt][ct], 0, 0, 0);
        #pragma unroll
        for (int nt = 0; nt < 4; ++nt)
            #pragma unroll
            for (int ct = 0; ct < 4; ++ct) {
                const int c = ct * 16 + qm, nn0 = nt * 16 + qk * 4;
                uint2 pk;
                pk.x = (u32)f2bf(acc[nt][ct][0]) | ((u32)f2bf(acc[nt][ct][1]) << 16);
                pk.y = (u32)f2bf(acc[nt][ct][2]) | ((u32)f2bf(acc[nt][ct][3]) << 16);
                *reinterpret_cast<uint2*>(&sh[c * 64 + nn0]) = pk;
            }
    }
    __syncthreads();

    {   // ---- serial inter-chunk hop, lane=n, batched: 16 reads ahead of chain
        float h = 0.f;
        u16* col = sh + lane;
        for (int b = 0; b < 4; ++b) {
            float sb[16];
            #pragma unroll
            for (int i = 0; i < 16; ++i) sb[i] = bf2f(col[(b * 16 + i) * 64]);
            #pragma unroll
            for (int i = 0; i < 16; ++i) {
                col[(b * 16 + i) * 64] = f2bf(h);
                h = rTn * h + dBn * sb[i];
            }
        }
    }
    __syncthreads();

    {   // ---- Y = KT_ext @ U_ext + P2 @ H ; epilogue adds Dp*u fp32, in-place
        bf16x8 Af[4][2];
        #pragma unroll
        for (int tt = 0; tt < 4; ++tt)
            #pragma unroll
            for (int jb = 0; jb < 2; ++jb)
                Af[tt][jb] = *reinterpret_cast<const bf16x8*>(
                    &KT_s[(tt * 16 + qm) * 64 + jb * 32 + qk * 8]);
        f32x4 acc[4][4] = {};
        #pragma unroll
        for (int kk = 0; kk < 4; ++kk)
            #pragma unroll
            for (int tt = 0; tt < 4; ++tt)
                #pragma unroll
                for (int ct = 0; ct < 4; ++ct)
                    acc[tt][ct] = __builtin_amdgcn_mfma_f32_16x16x32_bf16(
                        Af[tt][kk & 1], Uf[ct][kk], acc[tt][ct], 0, 0, 0);
        bf16x8 Pf[4][2];
        #pragma unroll
        for (int tt = 0; tt < 4; ++tt)
            #pragma unroll
            for (int kb = 0; kb < 2; ++kb)
                Pf[tt][kb] = *reinterpret_cast<const bf16x8*>(
                    &P2_s[(tt * 16 + qm) * 64 + kb * 32 + qk * 8]);
        #pragma unroll
        for (int ct = 0; ct < 4; ++ct)
            #pragma unroll
            for (int kb = 0; kb < 2; ++kb) {
                const bf16x8 Hf = *reinterpret_cast<const bf16x8*>(
                    &sh[(ct * 16 + qm) * 64 + kb * 32 + qk * 8]);
                #pragma unroll
                for (int tt = 0; tt < 4; ++tt)
                    acc[tt][ct] = __builtin_amdgcn_mfma_f32_16x16x32_bf16(
                        Pf[tt][kb], Hf, acc[tt][ct], 0, 0, 0);
            }
        #pragma unroll
        for (int tt = 0; tt < 4; ++tt)
            #pragma unroll
            for (int ct = 0; ct < 4; ++ct) {
                const int c = ct * 16 + qm, t0 = tt * 16 + qk * 4;
                float* dst = ug + c * 64 + t0;
                const float4 u4 = *reinterpret_cast<const float4*>(dst);
                float4 y;
                y.x = acc[tt][ct][0] + Dpd * u4.x;
                y.y = acc[tt][ct][1] + Dpd * u4.y;
                y.z = acc[tt][ct][2] + Dpd * u4.z;
                y.w = acc[tt][ct][3] + Dpd * u4.w;
                *reinterpret_cast<float4*>(dst) = y;
            }
    }
}

// ---------------------------------------------------------------------------
// transpose y_t[b][d][l] fp32 -> Ax rows [b*L][1024] bf16 for GEMM2.
// ---------------------------------------------------------------------------
__global__ __launch_bounds__(256) void trans_kernel(
    const float* __restrict__ yt, u16* __restrict__ Ax)
{
    __shared__ float T[64 * 68];
    const int b = blockIdx.z, dx = blockIdx.y * 64, lx = blockIdx.x * 64;
    const int tid = threadIdx.x;
    const int t16 = tid >> 4, l16 = tid & 15;
    #pragma unroll
    for (int ii = 0; ii < 4; ++ii) {
        const int dd = ii * 16 + t16;
        const int ll = l16 * 4;
        float4 v = *reinterpret_cast<const float4*>(
            &yt[((size_t)(b * D_MODEL + dx + dd)) * SEQ + lx + ll]);
        *reinterpret_cast<float4*>(&T[dd * 68 + ll]) = v;
    }
    __syncthreads();
    #pragma unroll
    for (int ii = 0; ii < 4; ++ii) {
        const int ll = ii * 16 + t16;
        const int dd = l16 * 4;
        float v0 = T[(dd + 0) * 68 + ll], v1 = T[(dd + 1) * 68 + ll];
        float v2 = T[(dd + 2) * 68 + ll], v3 = T[(dd + 3) * 68 + ll];
        const size_t row = (size_t)b * SEQ + lx + ll;
        *reinterpret_cast<uint2*>(Ax + row * D_MODEL + dx + dd) =
            make_uint2((u32)f2bf(v0) | ((u32)f2bf(v1) << 16),
                       (u32)f2bf(v2) | ((u32)f2bf(v3) << 16));
    }
}

// ---------------------------------------------------------------------------
// Workspace (60 MB):
//   [0,  24MB)  Ax (16MB used)
//   [24, 56MB)  ut : [b][d][l] fp32 (scan in-place -> y_t)
//   [56, 58MB)  Bw1 : Win bf16
//   [58, 60MB)  Bw2 : Wout bf16
// ---------------------------------------------------------------------------
extern "C" void kernel_launch(void* const* d_in, const int* in_sizes, int n_in,
                              void* d_out, int out_size, void* d_ws, size_t ws_size,
                              hipStream_t stream) {
    const float* x     = (const float*)d_in[0];
    const float* Win   = (const float*)d_in[1];
    const float* bin   = (const float*)d_in[2];
    const float* A_log = (const float*)d_in[3];
    const float* Bp    = (const float*)d_in[4];
    const float* Cp    = (const float*)d_in[5];
    const float* Dpv   = (const float*)d_in[6];
    const float* dtp   = (const float*)d_in[7];
    const float* Wout  = (const float*)d_in[8];
    const float* bout  = (const float*)d_in[9];
    float* out = (float*)d_out;

    char* ws = (char*)d_ws;
    u16*   Ax  = (u16*)(ws);
    float* ut  = (float*)(ws + (size_t)25165824);
    u16*   Bw1 = (u16*)(ws + (size_t)58720256);
    u16*   Bw2 = (u16*)(ws + (size_t)60817408);

    prep_kernel<<<MROWS + 2 * D_MODEL, 256, 0, stream>>>(x, Win, Wout, Ax, Bw1, Bw2);
    gemm_bt<1><<<dim3(D_MODEL / 128, MROWS / 128), 256, 0, stream>>>(Ax, Bw1, bin, ut);
    scan2_kernel<<<D_MODEL, 128, 0, stream>>>(ut, A_log, Bp, Cp, dtp, Dpv);
    trans_kernel<<<dim3(SEQ / 64, D_MODEL / 64, BATCH), 256, 0, stream>>>(ut, Ax);
    gemm_bt<0><<<dim3(D_MODEL / 128, MROWS / 128), 256, 0, stream>>>(Ax, Bw2, bout, out);
}

// Round 6
// 187.861 us; speedup vs baseline: 1.7419x; 1.0219x over previous
//
#include <hip/hip_runtime.h>
#include <cstdint>
#include <cstddef>

#define D_MODEL 1024
#define D_STATE 64
#define SEQ     4096
#define BATCH   2
#define MROWS   (BATCH*SEQ)   // 8192 rows of activations

typedef __bf16 bf16x8 __attribute__((ext_vector_type(8)));
typedef float  f32x4  __attribute__((ext_vector_type(4)));
typedef unsigned short u16;
typedef unsigned int   u32;

union BF8 { bf16x8 v; uint4 q; u16 e[8]; };

__device__ __forceinline__ u16 f2bf(float x) {
    u32 u = __float_as_uint(x);
    u32 r = u + 0x7FFFu + ((u >> 16) & 1u);   // RNE on bf16 boundary
    return (u16)(r >> 16);
}
__device__ __forceinline__ float bf2f(u16 h) {
    return __uint_as_float(((u32)h) << 16);
}
__device__ __forceinline__ uint4 pack8u(const u16* e) {
    return make_uint4((u32)e[0] | ((u32)e[1] << 16), (u32)e[2] | ((u32)e[3] << 16),
                      (u32)e[4] | ((u32)e[5] << 16), (u32)e[6] | ((u32)e[7] << 16));
}

// async global->LDS, 16B per lane. LDS dest is wave-uniform base + lane*16.
__device__ __forceinline__ void async16(const void* g, void* l) {
    __builtin_amdgcn_global_load_lds(
        (const __attribute__((address_space(1))) unsigned int*)(uintptr_t)g,
        (__attribute__((address_space(3))) unsigned int*)(uintptr_t)l,
        16, 0, 0);
}

// ---------------------------------------------------------------------------
// prep: flat fp32 -> bf16 convert over [ x | Win | Wout ] -> [ Ax | Bw1 | Bw2 ].
// All three are row-major [rows][1024]; boundaries are 4096-float multiples, so
// a flat mapping (block = 4096 floats) never straddles arrays.
// grid 2560 x 256 thr, 4 float4 per thread.
// ---------------------------------------------------------------------------
__global__ __launch_bounds__(256) void prep_kernel(
    const float* __restrict__ x, const float* __restrict__ Win,
    const float* __restrict__ Wout,
    u16* __restrict__ Ax, u16* __restrict__ Bw1, u16* __restrict__ Bw2)
{
    const size_t base = (size_t)blockIdx.x * 4096 + threadIdx.x * 4;
    const float* src; u16* dst; size_t off;
    if (base < 8388608)        { src = x;    dst = Ax;  off = base; }
    else if (base < 9437184)   { src = Win;  dst = Bw1; off = base - 8388608; }
    else                       { src = Wout; dst = Bw2; off = base - 9437184; }
    #pragma unroll
    for (int i = 0; i < 4; ++i) {
        const float4 v = *reinterpret_cast<const float4*>(src + off + i * 1024);
        *reinterpret_cast<uint2*>(dst + off + i * 1024) =
            make_uint2((u32)f2bf(v.x) | ((u32)f2bf(v.y) << 16),
                       (u32)f2bf(v.z) | ((u32)f2bf(v.w) << 16));
    }
}

// ---------------------------------------------------------------------------
// gemm_bt: out[m,c] = sum_k A[m,k]*Bm[c,k] + bias[c], K=1024 bf16.
// 128x128 tile, 4 waves (2x2 of 64x64), BK=64, mfma 16x16x32 bf16,
// double-buffered global_load_lds staging (one barrier per K-iter).
// XCD swizzle: 1D grid 512, bid&7 = XCD (round-robin dispatch); each XCD gets
// 8 complete m-strips x all 8 n-blocks -> per-XCD L2 working set = 2MB A + 2MB B
// = 4MB L2. A fetched from HBM ~once instead of ~4-8x (R2: FETCH 133MB vs 34
// unique), and staging loads become L2 hits -> barrier drain shrinks too.
// MODE 0: fp32 [m][1024] coalesced store. MODE 1: transposed store into
// ut[b][c][l] via per-wave LDS patch.
// ---------------------------------------------------------------------------
template<int MODE>
__global__ __launch_bounds__(256) void gemm_bt(
    const u16* __restrict__ A, const u16* __restrict__ Bm,
    const float* __restrict__ bias, float* __restrict__ out)
{
    __shared__ __align__(16) u16 As[2][128 * 64];
    __shared__ __align__(16) u16 Bs[2][128 * 64];
    const int bid  = blockIdx.x;
    const int slot = bid >> 3;
    const int m0 = ((bid & 7) * 8 + (slot >> 3)) * 128;   // XCD-grouped m-strips
    const int n0 = (slot & 7) * 128;
    const int tid = threadIdx.x;
    const int wave = tid >> 6, lane = tid & 63;
    const int wm = wave >> 1, wn = wave & 1;
    const int qm = lane & 15, qk = lane >> 4;
    f32x4 acc[4][4] = {};

    auto stage = [&](u16* Ad, u16* Bd, int k0) {
        #pragma unroll
        for (int it = 0; it < 4; ++it) {
            const int c   = it * 256 + tid;          // chunk 0..1023 (16B each)
            const int row = c >> 3, col = (c & 7) * 8;
            const int ldsbase = (it * 256 + wave * 64) * 8;   // wave-uniform
            async16(&A[(size_t)(m0 + row) * D_MODEL + k0 + col], Ad + ldsbase);
            async16(&Bm[(size_t)(n0 + row) * D_MODEL + k0 + col], Bd + ldsbase);
        }
    };
    auto compute = [&](const u16* As_, const u16* Bs_) {
        #pragma unroll
        for (int kk = 0; kk < 2; ++kk) {
            bf16x8 af[4], bg[4];
            #pragma unroll
            for (int i = 0; i < 4; ++i) {
                af[i] = *reinterpret_cast<const bf16x8*>(&As_[(wm*64 + i*16 + qm)*64 + kk*32 + qk*8]);
                bg[i] = *reinterpret_cast<const bf16x8*>(&Bs_[(wn*64 + i*16 + qm)*64 + kk*32 + qk*8]);
            }
            #pragma unroll
            for (int i = 0; i < 4; ++i)
                #pragma unroll
                for (int j = 0; j < 4; ++j)
                    acc[i][j] = __builtin_amdgcn_mfma_f32_16x16x32_bf16(af[i], bg[j], acc[i][j], 0, 0, 0);
        }
    };

    stage(As[0], Bs[0], 0);
    __syncthreads();
    #pragma unroll 1
    for (int kp = 0; kp < 7; ++kp) {
        stage(As[1], Bs[1], 128 * kp + 64);
        compute(As[0], Bs[0]);
        __syncthreads();
        stage(As[0], Bs[0], 128 * kp + 128);
        compute(As[1], Bs[1]);
        __syncthreads();
    }
    stage(As[1], Bs[1], 960);
    compute(As[0], Bs[0]);      // k=896
    __syncthreads();
    compute(As[1], Bs[1]);      // k=960

    // C/D layout: col = lane&15, row = (lane>>4)*4 + reg  [m89/m91-verified]
    if (MODE == 0) {
        #pragma unroll
        for (int i = 0; i < 4; ++i) {
            const int r0 = m0 + wm*64 + i*16 + qk*4;
            #pragma unroll
            for (int j = 0; j < 4; ++j) {
                const int c = n0 + wn*64 + j*16 + qm;
                const float bv = bias[c];
                #pragma unroll
                for (int reg = 0; reg < 4; ++reg)
                    out[(size_t)(r0 + reg) * D_MODEL + c] = acc[i][j][reg] + bv;
            }
        }
    } else {
        // As[0..] aliased as fp32 transpose patch (16.6KB; spills 256B into
        // As[1] which is dead after the final compute).
        float* Tt = reinterpret_cast<float*>(&As[0][0]);   // 4 waves x 16x65 fp32
        float* T = &Tt[wave * 16 * 65];
        float bvj[4];
        #pragma unroll
        for (int j = 0; j < 4; ++j) bvj[j] = bias[n0 + wn*64 + j*16 + qm];
        const int dcol = n0 + wn*64 + lane;            // read-phase column (d)
        #pragma unroll
        for (int i = 0; i < 4; ++i) {
            #pragma unroll
            for (int j = 0; j < 4; ++j)
                #pragma unroll
                for (int reg = 0; reg < 4; ++reg)
                    T[(qk*4 + reg) * 65 + j*16 + qm] = acc[i][j][reg] + bvj[j];
            __builtin_amdgcn_wave_barrier();
            float4 o[4];
            #pragma unroll
            for (int t4 = 0; t4 < 4; ++t4)
                o[t4] = make_float4(T[(t4*4 + 0) * 65 + lane], T[(t4*4 + 1) * 65 + lane],
                                    T[(t4*4 + 2) * 65 + lane], T[(t4*4 + 3) * 65 + lane]);
            const int r0 = m0 + wm*64 + i*16;
            const int bb = r0 >> 12, l0 = r0 & (SEQ - 1);
            float* dst = &out[((size_t)(bb * D_MODEL + dcol)) * SEQ + l0];
            #pragma unroll
            for (int t4 = 0; t4 < 4; ++t4)
                reinterpret_cast<float4*>(dst)[t4] = o[t4];
            __builtin_amdgcn_wave_barrier();
        }
    }
}

// ---------------------------------------------------------------------------
// scan2: MFMA chunked scan, fused in-LDS table build. 1024 blocks x 128 thr.
// LDS = 5 x 64x64 u16 = 40960 B -> exactly 4 blocks/CU (matches grid 4/CU).
// (unchanged from R5 — verified)
// ---------------------------------------------------------------------------
__global__ __launch_bounds__(128) void scan2_kernel(
    float* __restrict__ ut, const float* __restrict__ A_log,
    const float* __restrict__ Bp, const float* __restrict__ Cp,
    const float* __restrict__ dtp, const float* __restrict__ Dpv)
{
    __shared__ __align__(16) u16 KT_s[64 * 64];
    __shared__ __align__(16) u16 RA_s[64 * 64];
    __shared__ __align__(16) u16 P2_s[64 * 64];
    __shared__ __align__(16) u16 SH[2][64 * 64];   // scratch during build; S/H after
    const int d = blockIdx.x, tid = threadIdx.x;
    const int w = tid >> 6, lane = tid & 63;
    const int qm = lane & 15, qk = lane >> 4;

    const float dt_d  = dtp[d];
    const float logdA = -expf(-A_log[d * D_STATE + lane]) * dt_d;
    const float r     = expf(logdA);
    const float dBn   = Bp[d * D_STATE + lane] * dt_d;
    const float Cv    = Cp[d * D_STATE + lane];
    const float rTn   = expf(logdA * 64.0f);
    const float Dpd   = Dpv[d];

    float* ug = ut + ((size_t)(w * D_MODEL + d)) * SEQ;

    // fp32 scratch inside SH (dead until S-phase): dB[64] | w[64] | k[64]
    float* dB_sh = reinterpret_cast<float*>(&SH[0][0]);
    float* w_sh  = dB_sh + 64;
    float* k_sh  = dB_sh + 128;

    // ---- U B-fragments (global fp32 -> hi/lo bf16), kk 0..1 = hi, 2..3 = lo
    bf16x8 Uf[4][4];
    #pragma unroll
    for (int ct = 0; ct < 4; ++ct) {
        const float* src = ug + (ct * 16 + qm) * 64;
        #pragma unroll
        for (int jb = 0; jb < 2; ++jb) {
            const float4 v0 = *reinterpret_cast<const float4*>(src + jb * 32 + qk * 8);
            const float4 v1 = *reinterpret_cast<const float4*>(src + jb * 32 + qk * 8 + 4);
            const float fv[8] = {v0.x, v0.y, v0.z, v0.w, v1.x, v1.y, v1.z, v1.w};
            BF8 hi, lo;
            #pragma unroll
            for (int i = 0; i < 8; ++i) {
                hi.e[i] = f2bf(fv[i]);
                lo.e[i] = f2bf(fv[i] - bf2f(hi.e[i]));
            }
            Uf[ct][jb]     = hi.v;
            Uf[ct][jb + 2] = lo.v;
        }
    }

    // ---- table build phase 1
    if (w == 0) {
        dB_sh[lane] = dBn;
        w_sh[lane]  = Cv * dBn;
        for (int o = 0; o < 8; ++o) {   // RA row n=lane: r^(63-j), j ascending
            float tmp[8];
            tmp[7] = expf(logdA * (float)(63 - (o * 8 + 7)));
            #pragma unroll
            for (int i = 6; i >= 0; --i) tmp[i] = tmp[i + 1] * r;
            u16 e[8];
            #pragma unroll
            for (int i = 0; i < 8; ++i) e[i] = f2bf(tmp[i]);
            *reinterpret_cast<uint4*>(&RA_s[lane * 64 + o * 8]) = pack8u(e);
        }
    } else {
        float p = Cv;                   // P2 column n=lane: C r^{t+1}
        for (int t = 0; t < 64; ++t) { p *= r; P2_s[t * 64 + lane] = f2bf(p); }
    }
    __syncthreads();
    // ---- table build phase 2 (wave0): k from P2, then KT rows
    if (w == 0) {
        float kacc = 0.f;
        if (lane == 0) {
            for (int n = 0; n < 64; ++n) kacc += w_sh[n];
        } else {
            const u16* prow = &P2_s[(lane - 1) * 64];
            for (int o = 0; o < 8; ++o) {
                BF8 p8; p8.q = *reinterpret_cast<const uint4*>(&prow[o * 8]);
                #pragma unroll
                for (int i = 0; i < 8; ++i) kacc += dB_sh[o * 8 + i] * bf2f(p8.e[i]);
            }
        }
        k_sh[lane] = kacc;              // same-wave LDS: in-order visibility
        for (int o = 0; o < 8; ++o) {   // KT row t=lane
            u16 e[8];
            #pragma unroll
            for (int i = 0; i < 8; ++i) {
                const int j = o * 8 + i;
                e[i] = (j <= lane) ? f2bf(k_sh[lane - j]) : (u16)0;
            }
            *reinterpret_cast<uint4*>(&KT_s[lane * 64 + o * 8]) = pack8u(e);
        }
    }
    __syncthreads();

    u16* sh = SH[w];
    {   // ---- S = RA_ext @ U_ext -> SH[w][c][n] bf16
        bf16x8 Af[4][2];
        #pragma unroll
        for (int nt = 0; nt < 4; ++nt)
            #pragma unroll
            for (int jb = 0; jb < 2; ++jb)
                Af[nt][jb] = *reinterpret_cast<const bf16x8*>(
                    &RA_s[(nt * 16 + qm) * 64 + jb * 32 + qk * 8]);
        f32x4 acc[4][4] = {};
        #pragma unroll
        for (int kk = 0; kk < 4; ++kk)
            #pragma unroll
            for (int nt = 0; nt < 4; ++nt)
                #pragma unroll
                for (int ct = 0; ct < 4; ++ct)
                    acc[nt][ct] = __builtin_amdgcn_mfma_f32_16x16x32_bf16(
                        Af[nt][kk & 1], Uf[ct][kk], acc[nt][ct], 0, 0, 0);
        #pragma unroll
        for (int nt = 0; nt < 4; ++nt)
            #pragma unroll
            for (int ct = 0; ct < 4; ++ct) {
                const int c = ct * 16 + qm, nn0 = nt * 16 + qk * 4;
                uint2 pk;
                pk.x = (u32)f2bf(acc[nt][ct][0]) | ((u32)f2bf(acc[nt][ct][1]) << 16);
                pk.y = (u32)f2bf(acc[nt][ct][2]) | ((u32)f2bf(acc[nt][ct][3]) << 16);
                *reinterpret_cast<uint2*>(&sh[c * 64 + nn0]) = pk;
            }
    }
    __syncthreads();

    {   // ---- serial inter-chunk hop, lane=n, batched: 16 reads ahead of chain
        float h = 0.f;
        u16* col = sh + lane;
        for (int b = 0; b < 4; ++b) {
            float sb[16];
            #pragma unroll
            for (int i = 0; i < 16; ++i) sb[i] = bf2f(col[(b * 16 + i) * 64]);
            #pragma unroll
            for (int i = 0; i < 16; ++i) {
                col[(b * 16 + i) * 64] = f2bf(h);
                h = rTn * h + dBn * sb[i];
            }
        }
    }
    __syncthreads();

    {   // ---- Y = KT_ext @ U_ext + P2 @ H ; epilogue adds Dp*u fp32, in-place
        bf16x8 Af[4][2];
        #pragma unroll
        for (int tt = 0; tt < 4; ++tt)
            #pragma unroll
            for (int jb = 0; jb < 2; ++jb)
                Af[tt][jb] = *reinterpret_cast<const bf16x8*>(
                    &KT_s[(tt * 16 + qm) * 64 + jb * 32 + qk * 8]);
        f32x4 acc[4][4] = {};
        #pragma unroll
        for (int kk = 0; kk < 4; ++kk)
            #pragma unroll
            for (int tt = 0; tt < 4; ++tt)
                #pragma unroll
                for (int ct = 0; ct < 4; ++ct)
                    acc[tt][ct] = __builtin_amdgcn_mfma_f32_16x16x32_bf16(
                        Af[tt][kk & 1], Uf[ct][kk], acc[tt][ct], 0, 0, 0);
        bf16x8 Pf[4][2];
        #pragma unroll
        for (int tt = 0; tt < 4; ++tt)
            #pragma unroll
            for (int kb = 0; kb < 2; ++kb)
                Pf[tt][kb] = *reinterpret_cast<const bf16x8*>(
                    &P2_s[(tt * 16 + qm) * 64 + kb * 32 + qk * 8]);
        #pragma unroll
        for (int ct = 0; ct < 4; ++ct)
            #pragma unroll
            for (int kb = 0; kb < 2; ++kb) {
                const bf16x8 Hf = *reinterpret_cast<const bf16x8*>(
                    &sh[(ct * 16 + qm) * 64 + kb * 32 + qk * 8]);
                #pragma unroll
                for (int tt = 0; tt < 4; ++tt)
                    acc[tt][ct] = __builtin_amdgcn_mfma_f32_16x16x32_bf16(
                        Pf[tt][kb], Hf, acc[tt][ct], 0, 0, 0);
            }
        #pragma unroll
        for (int tt = 0; tt < 4; ++tt)
            #pragma unroll
            for (int ct = 0; ct < 4; ++ct) {
                const int c = ct * 16 + qm, t0 = tt * 16 + qk * 4;
                float* dst = ug + c * 64 + t0;
                const float4 u4 = *reinterpret_cast<const float4*>(dst);
                float4 y;
                y.x = acc[tt][ct][0] + Dpd * u4.x;
                y.y = acc[tt][ct][1] + Dpd * u4.y;
                y.z = acc[tt][ct][2] + Dpd * u4.z;
                y.w = acc[tt][ct][3] + Dpd * u4.w;
                *reinterpret_cast<float4*>(dst) = y;
            }
    }
}

// ---------------------------------------------------------------------------
// transpose y_t[b][d][l] fp32 -> Ax rows [b*L][1024] bf16 for GEMM2.
// (unchanged — verified)
// ---------------------------------------------------------------------------
__global__ __launch_bounds__(256) void trans_kernel(
    const float* __restrict__ yt, u16* __restrict__ Ax)
{
    __shared__ float T[64 * 68];
    const int b = blockIdx.z, dx = blockIdx.y * 64, lx = blockIdx.x * 64;
    const int tid = threadIdx.x;
    const int t16 = tid >> 4, l16 = tid & 15;
    #pragma unroll
    for (int ii = 0; ii < 4; ++ii) {
        const int dd = ii * 16 + t16;
        const int ll = l16 * 4;
        float4 v = *reinterpret_cast<const float4*>(
            &yt[((size_t)(b * D_MODEL + dx + dd)) * SEQ + lx + ll]);
        *reinterpret_cast<float4*>(&T[dd * 68 + ll]) = v;
    }
    __syncthreads();
    #pragma unroll
    for (int ii = 0; ii < 4; ++ii) {
        const int ll = ii * 16 + t16;
        const int dd = l16 * 4;
        float v0 = T[(dd + 0) * 68 + ll], v1 = T[(dd + 1) * 68 + ll];
        float v2 = T[(dd + 2) * 68 + ll], v3 = T[(dd + 3) * 68 + ll];
        const size_t row = (size_t)b * SEQ + lx + ll;
        *reinterpret_cast<uint2*>(Ax + row * D_MODEL + dx + dd) =
            make_uint2((u32)f2bf(v0) | ((u32)f2bf(v1) << 16),
                       (u32)f2bf(v2) | ((u32)f2bf(v3) << 16));
    }
}

// ---------------------------------------------------------------------------
// Workspace (60 MB):
//   [0,  24MB)  Ax (16MB used)
//   [24, 56MB)  ut : [b][d][l] fp32 (scan in-place -> y_t)
//   [56, 58MB)  Bw1 : Win bf16
//   [58, 60MB)  Bw2 : Wout bf16
// ---------------------------------------------------------------------------
extern "C" void kernel_launch(void* const* d_in, const int* in_sizes, int n_in,
                              void* d_out, int out_size, void* d_ws, size_t ws_size,
                              hipStream_t stream) {
    const float* x     = (const float*)d_in[0];
    const float* Win   = (const float*)d_in[1];
    const float* bin   = (const float*)d_in[2];
    const float* A_log = (const float*)d_in[3];
    const float* Bp    = (const float*)d_in[4];
    const float* Cp    = (const float*)d_in[5];
    const float* Dpv   = (const float*)d_in[6];
    const float* dtp   = (const float*)d_in[7];
    const float* Wout  = (const float*)d_in[8];
    const float* bout  = (const float*)d_in[9];
    float* out = (float*)d_out;

    char* ws = (char*)d_ws;
    u16*   Ax  = (u16*)(ws);
    float* ut  = (float*)(ws + (size_t)25165824);
    u16*   Bw1 = (u16*)(ws + (size_t)58720256);
    u16*   Bw2 = (u16*)(ws + (size_t)60817408);

    prep_kernel<<<2560, 256, 0, stream>>>(x, Win, Wout, Ax, Bw1, Bw2);
    gemm_bt<1><<<512, 256, 0, stream>>>(Ax, Bw1, bin, ut);
    scan2_kernel<<<D_MODEL, 128, 0, stream>>>(ut, A_log, Bp, Cp, dtp, Dpv);
    trans_kernel<<<dim3(SEQ / 64, D_MODEL / 64, BATCH), 256, 0, stream>>>(ut, Ax);
    gemm_bt<0><<<512, 256, 0, stream>>>(Ax, Bw2, bout, out);
}